// Round 12
// baseline (462.476 us; speedup 1.0000x reference)
//
#include <hip/hip_runtime.h>
#include <math.h>

// ---------------------------------------------------------------------------
// SlotAttention fused forward. MFMA (bf16) attention path.
//   CACHE mode: iter0 computes xs = rs*x (bf16), stores the exact LDS chunk
//   image (16KB, unpadded) to ws; iters 1-2 reload with coalesced uint4 loads
//   (half bytes, zero pack VALU). logit = dot(xs,w'') - rm*c1 + c0; P = a.
//   Fallback (ws too small): r11 path (raw-x bf16, rs in epilogue).
//   A0/A1: per-block partials to apart (no contended atomics), reduced in vred.
//   V partials: bf16 pk2 to vpart, reduced by k_vred.
//   GRU/MLP: gx = yflat @ Wfold^T; k_gates + fused k_mlp (unchanged from r11).
// ---------------------------------------------------------------------------

#define NKV   4096
#define DD    256
#define HQN   32
#define EPSR  1e-8f

// workspace layout (float offsets)
#define WS_V      0                     // 262144
#define WS_A0     262144                // 1024
#define WS_A1     263168                // 1024
#define WS_C0     264192                // 1024
#define WS_C1     265216                // 1024
#define WS_SLOTA  266240                // 65536
#define WS_SLOTB  331776                // 65536
#define WS_WQT    397312                // 65536 fp32 Wq^T
#define WS_WPGXH  462848                // 393216 (wp_bf 131072f | gxh [256][1536])
#define WS_WFT    856064                // 393216 uints: WfoldT2 [512][768]
#define WS_WHHT   1249280               // 98304 uints:  WhhT2   [128][768]
#define WS_W1T    1347584               // 131072 uints: W1T2    [128][1024]
#define WS_W2T    1478656               // 131072 uints: W2T2    [512][256]
#define WS_RS     1609728               // 131072 fp32 rs per token (fallback only)
#define WS_RM     1740800               // 131072 fp32 rm per token
#define WS_VPART  1871872               // 8388608 uints: Vpart bf16x2, 32MB
#define WS_APART  10260480              // 262144 fp32: apart[2048 blk][128]
#define WS_XC     10522624              // 16777216 f: xs cache (4096 chunks x 16KB)
#define WS_NEED_BYTE ((size_t)(10522624 + 16777216) * 4)   // 109.2 MB

typedef float f32x4 __attribute__((ext_vector_type(4)));
typedef short s16x8 __attribute__((ext_vector_type(8)));
typedef int   v2i   __attribute__((ext_vector_type(2)));

__device__ __forceinline__ unsigned bfr(float f) {
    unsigned u = __float_as_uint(f);
    return (u + 0x7fffu + ((u >> 16) & 1u)) >> 16;
}
__device__ __forceinline__ unsigned pk2(float lo, float hi) {
    return bfr(lo) | (bfr(hi) << 16);
}
__device__ __forceinline__ float bf2f(unsigned short us) {
    return __uint_as_float((unsigned)us << 16);
}
__device__ __forceinline__ float bflo(unsigned u) { return __uint_as_float(u << 16); }
__device__ __forceinline__ float bfhi(unsigned u) { return __uint_as_float(u & 0xffff0000u); }

__device__ __forceinline__ v2i tr_read(unsigned addr) {
    v2i d;
    asm volatile("ds_read_b64_tr_b16 %0, %1" : "=v"(d) : "v"(addr));
    return d;
}
__device__ __forceinline__ s16x8 mk_frag(v2i a, v2i b) {
    union { int i[4]; s16x8 s; } u;
    u.i[0] = a.x; u.i[1] = a.y; u.i[2] = b.x; u.i[3] = b.y;
    return u.s;
}

__global__ __launch_bounds__(256) void k_copy(const float* __restrict__ in,
                                              float* __restrict__ out, int n) {
    int i = blockIdx.x * 256 + threadIdx.x;
    if (i < n) out[i] = in[i];
}

// generic 32x32 tiled fp32 transpose: in[R][C] -> out[C][R]
__global__ __launch_bounds__(256) void k_tr(const float* __restrict__ in,
                                            float* __restrict__ out, int R, int C) {
    __shared__ float tile[32][33];
    int bx = blockIdx.x * 32, by = blockIdx.y * 32;
    int x = bx + threadIdx.x;
    for (int k = 0; k < 32; k += 8) {
        int y = by + threadIdx.y + k;
        if (x < C && y < R) tile[threadIdx.y + k][threadIdx.x] = in[(size_t)y * C + x];
    }
    __syncthreads();
    int r = by + threadIdx.x;
    for (int k = 0; k < 32; k += 8) {
        int c = bx + threadIdx.y + k;
        if (c < C && r < R) out[(size_t)c * R + r] = tile[threadIdx.x][threadIdx.y + k];
    }
}

// ---------------------------------------------------------------------------
// Wfold: one block per output row c.
__global__ __launch_bounds__(256) void k_wfold(
    const float* __restrict__ Wih, const float* __restrict__ Wv,
    unsigned* __restrict__ WfT2)
{
    __shared__ float wr[256];
    const int c = blockIdx.x, t = threadIdx.x;
    wr[t] = Wih[(size_t)c * 256 + t];
    __syncthreads();
    const float2* wv2 = (const float2*)Wv;
    #pragma unroll
    for (int pp = 0; pp < 2; ++pp) {
        int P = pp * 256 + t;
        int h = P >> 7, p = P & 127;
        float f0 = 0.f, f1 = 0.f;
        #pragma unroll 8
        for (int d = 0; d < 64; ++d) {
            float a = wr[h * 64 + d];
            float2 v = wv2[(size_t)(h * 64 + d) * 128 + p];
            f0 = fmaf(a, v.x, f0); f1 = fmaf(a, v.y, f1);
        }
        WfT2[(size_t)P * 768 + c] = pk2(f0, f1);
    }
}

// transpose+pack: in fp32 [R][C] -> out uint [C/2][R]
__global__ __launch_bounds__(256) void k_trpack(
    const float* __restrict__ in, unsigned* __restrict__ out, int R, int C)
{
    const int c2 = blockIdx.x;
    const int t = threadIdx.x;
    for (int q = 0; q < R / 256; ++q) {
        int r = q * 256 + t;
        out[(size_t)c2 * R + r] = pk2(in[(size_t)r * C + 2 * c2],
                                      in[(size_t)r * C + 2 * c2 + 1]);
    }
}

// ---------------------------------------------------------------------------
// Merged slot prep: grid (32 b, 4 h).
__global__ __launch_bounds__(256) void k_prep(
    const float* __restrict__ slots, const float* __restrict__ g_s, const float* __restrict__ b_s,
    const float* __restrict__ wqt, const float* __restrict__ Wk,
    const float* __restrict__ g_in, const float* __restrict__ b_in,
    unsigned short* __restrict__ wp_bf, float* __restrict__ c0_g, float* __restrict__ c1_g)
{
    __shared__ float s_lds[2048];
    __shared__ float qs[512];
    __shared__ float redc[4096];
    const int t = threadIdx.x;
    const int b = blockIdx.x, h = blockIdx.y;
    const int lane = t & 63, w = t >> 6;
    const float LNS = 0.125f * 1.44269504f;

    for (int r = w; r < 8; r += 4) {
        const float4 v = ((const float4*)(slots + ((size_t)b * 8 + r) * 256))[lane];
        float s0 = v.x + v.y + v.z + v.w;
        float s1 = v.x * v.x + v.y * v.y + v.z * v.z + v.w * v.w;
        #pragma unroll
        for (int o = 32; o >= 1; o >>= 1) { s0 += __shfl_xor(s0, o, 64); s1 += __shfl_xor(s1, o, 64); }
        float m = s0 * (1.f / 256.f);
        float rs = rsqrtf(s1 * (1.f / 256.f) - m * m + 1e-5f);
        float4 gg = ((const float4*)g_s)[lane];
        float4 bb = ((const float4*)b_s)[lane];
        float4 nn;
        nn.x = (v.x - m) * rs * gg.x + bb.x;
        nn.y = (v.y - m) * rs * gg.y + bb.y;
        nn.z = (v.z - m) * rs * gg.z + bb.z;
        nn.w = (v.w - m) * rs * gg.w + bb.w;
        ((float4*)(s_lds + r * 256))[lane] = nn;
    }
    __syncthreads();

    {
        const int qi0 = t >> 6, d = t & 63;
        float a0 = 0.f, a1 = 0.f;
        #pragma unroll 8
        for (int j = 0; j < 256; ++j) {
            float wv = wqt[j * 256 + h * 64 + d];
            a0 = fmaf(s_lds[qi0 * 256 + j], wv, a0);
            a1 = fmaf(s_lds[(qi0 + 4) * 256 + j], wv, a1);
        }
        qs[qi0 * 64 + d] = a0;
        qs[(qi0 + 4) * 64 + d] = a1;
    }
    __syncthreads();

    float a2[8];
    #pragma unroll
    for (int qi = 0; qi < 8; ++qi) a2[qi] = 0.f;
    #pragma unroll 4
    for (int d = 0; d < 64; ++d) {
        float wv = Wk[(size_t)(h * 64 + d) * 256 + t];
        #pragma unroll
        for (int qi = 0; qi < 8; ++qi) a2[qi] = fmaf(qs[qi * 64 + d], wv, a2[qi]);
    }
    const float gv = g_in[t], bv = b_in[t];
    #pragma unroll
    for (int qi = 0; qi < 8; ++qi) {
        float kv = LNS * a2[qi];
        float we = kv * gv;
        wp_bf[((size_t)b * HQN + h * 8 + qi) * 256 + t] = (unsigned short)bfr(we);
        redc[qi * 256 + t] = we;
        redc[2048 + qi * 256 + t] = kv * bv;
    }
    __syncthreads();
    #pragma unroll
    for (int rep = 0; rep < 2; ++rep) {
        int r = w * 2 + rep;
        float sv1 = redc[r * 256 + lane] + redc[r * 256 + 64 + lane] +
                    redc[r * 256 + 128 + lane] + redc[r * 256 + 192 + lane];
        float sv0 = redc[2048 + r * 256 + lane] + redc[2048 + r * 256 + 64 + lane] +
                    redc[2048 + r * 256 + 128 + lane] + redc[2048 + r * 256 + 192 + lane];
        #pragma unroll
        for (int o = 32; o >= 1; o >>= 1) {
            sv1 += __shfl_xor(sv1, o, 64);
            sv0 += __shfl_xor(sv0, o, 64);
        }
        if (lane == 0) {
            c1_g[b * 32 + h * 8 + r] = sv1;
            c0_g[b * 32 + h * 8 + r] = sv0;
        }
    }
}

// ---------------------------------------------------------------------------
// k_attn helpers
__device__ __forceinline__ void load_x(const float* __restrict__ inp, int b, int n0,
                                       int tok_s, int seg8, float4* ld) {
    const float4* row4 = (const float4*)(inp + ((size_t)b * NKV + n0 + tok_s) * 256);
    #pragma unroll
    for (int u = 0; u < 8; ++u) ld[u] = row4[(u >> 2) * 32 + seg8 * 4 + (u & 3)];
}

// pack raw (fallback) or scaled (cache) bf16 into xb image
__device__ __forceinline__ void pack_x(const float4* ld, char* dst, int tok_s, int seg8,
                                       float sc) {
    #pragma unroll
    for (int c = 0; c < 2; ++c) {
        int nt = seg8 + 8 * c;
        #pragma unroll
        for (int h = 0; h < 2; ++h) {
            float4 fa = ld[c * 4 + h * 2], fb = ld[c * 4 + h * 2 + 1];
            uint4 pk;
            pk.x = pk2(sc * fa.x, sc * fa.y); pk.y = pk2(sc * fa.z, sc * fa.w);
            pk.z = pk2(sc * fb.x, sc * fb.y); pk.w = pk2(sc * fb.z, sc * fb.w);
            *(uint4*)(dst + nt * 1040 + tok_s * 32 + h * 16) = pk;
        }
    }
}

// fallback stats: writes rs->sb[tok], rm->sb[32+tok], rs_g, rm_g; returns rs
__device__ __forceinline__ float calc_stats(const float4* ld, float* sb,
                                            float* __restrict__ rs_g, float* __restrict__ rm_g,
                                            int b, int n0, int tok_s, int seg8, int cachemode) {
    float s0 = 0.f, s1 = 0.f;
    #pragma unroll
    for (int u = 0; u < 8; ++u) {
        float4 v = ld[u];
        s0 += v.x + v.y + v.z + v.w;
        s1 = fmaf(v.x, v.x, s1); s1 = fmaf(v.y, v.y, s1);
        s1 = fmaf(v.z, v.z, s1); s1 = fmaf(v.w, v.w, s1);
    }
    s0 += __shfl_xor(s0, 1, 64); s1 += __shfl_xor(s1, 1, 64);
    s0 += __shfl_xor(s0, 2, 64); s1 += __shfl_xor(s1, 2, 64);
    s0 += __shfl_xor(s0, 4, 64); s1 += __shfl_xor(s1, 4, 64);
    float m  = s0 * (1.f / 256.f);
    float rs = rsqrtf(s1 * (1.f / 256.f) - m * m + 1e-5f);
    if (seg8 == 0) {
        if (cachemode) {
            sb[tok_s] = rs * m;
        } else {
            sb[tok_s] = rs;
            sb[32 + tok_s] = rs * m;
            rs_g[b * 4096 + n0 + tok_s] = rs;
        }
        rm_g[b * 4096 + n0 + tok_s] = rs * m;
    }
    return rs;
}

// ---------------------------------------------------------------------------
// Main fused MFMA pass. grid (64, 32): NC=2 chunks of 32 tokens per block.
// CACHE=1: xs-scaled bf16 chunk images in ws (iter0 writes, iters 1-2 read).
template<int NC, int CACHE, int STATS, int WVIS>
__global__ __launch_bounds__(256) void k_attn(
    const float* __restrict__ inp, const unsigned short* __restrict__ wp_bf,
    const float* __restrict__ c0_g, const float* __restrict__ c1_g,
    unsigned* __restrict__ vpart, float* __restrict__ apart,
    float* __restrict__ rs_g, float* __restrict__ rm_g,
    uint4* __restrict__ xcache,
    float* __restrict__ out_vis, float* __restrict__ out_temp)
{
    constexpr int KBMAX = 128 / NC;
    __shared__ unsigned short xb[8320];         // 16640 B single buffer
    __shared__ unsigned short wl[8192];         // [hq][k] swizzled
    __shared__ unsigned short pt[1024];         // [hq][tok] bf16 P
    __shared__ float stats[2][64];
    __shared__ float redm[64];
    __shared__ float reds[64];

    const int t = threadIdx.x;
    const int l = t & 63, w = t >> 6;
    const int g = l >> 4, li = l & 15;
    const int b = blockIdx.y, kb = blockIdx.x;

    char* xbB = (char*)xb;
    char* wlB = (char*)wl;
    char* ptB = (char*)pt;
    const int tok_s = t >> 3, seg8 = t & 7;
    const int cbase = kb * NC;

    // stage W'' into LDS (swizzled rows [hq][k])
    {
        const uint4* wp4 = (const uint4*)wp_bf + ((size_t)b * 8192 + (t >> 3) * 256 + (t & 7) * 32) / 8;
        const int hq = t >> 3, sg = t & 7;
        #pragma unroll
        for (int q = 0; q < 4; ++q) {
            uint4 v = wp4[q];
            *(uint4*)(wlB + hq * 512 + (((sg * 4 + q) ^ (hq & 7)) * 16)) = v;
        }
    }

    const int Mt = w & 1, Nt = w >> 1;
    const int hqB = Nt * 16 + li;
    const float c0r = c0_g[b * 32 + hqB];
    const float c1r = c1_g[b * 32 + hqB];
    const int MtV = w >> 1, ntb = (w & 1) * 8;
    const int hqA = MtV * 16 + li;

    f32x4 av[8];
    #pragma unroll
    for (int u = 0; u < 8; ++u) av[u] = (f32x4){0.f, 0.f, 0.f, 0.f};
    float A0acc = 0.f, A1acc = 0.f;

    const unsigned xbase = (unsigned)(uintptr_t)xbB;
    // cache image LDS offset for copy: subtile (q*4+w), lane l
    const int img_ld = (0) ;

    // ---- prologue ----
    if (CACHE && !STATS) {
        if (t < 32 * NC) stats[t >> 5][t & 31] = rm_g[b * 4096 + cbase * 32 + t];
        uint4 cv[4];
        const uint4* cp = xcache + (size_t)(b * 128 + cbase) * 1024;
        #pragma unroll
        for (int q = 0; q < 4; ++q) cv[q] = cp[q * 256 + t];
        #pragma unroll
        for (int q = 0; q < 4; ++q)
            *(uint4*)(xbB + (q * 4 + w) * 1040 + l * 16) = cv[q];
    } else {
        float4 ldA[8];
        load_x(inp, b, cbase * 32, tok_s, seg8, ldA);
        float rs = 1.f;
        if (STATS) {
            rs = calc_stats(ldA, &stats[0][0], rs_g, rm_g, b, cbase * 32, tok_s, seg8, CACHE);
        } else {
            if (t < 32) stats[0][t] = rs_g[b * 4096 + cbase * 32 + t];
            else if (t < 64) stats[0][t] = rm_g[b * 4096 + cbase * 32 + t - 32];
        }
        pack_x(ldA, xbB, tok_s, seg8, CACHE ? rs : 1.f);
    }
    __syncthreads();   // A

    #pragma unroll
    for (int ci = 0; ci < NC; ++ci) {
        const int cur = ci & 1, nxt = cur ^ 1;
        const int sidx = (CACHE && !STATS) ? ci : cur;
        const int n0 = (cbase + ci) * 32;
        const int cid = b * 128 + cbase + ci;

        // ---- prefetch next chunk ----
        float4 ldN[8];
        uint4 cvN[4];
        if (ci < NC - 1) {
            if (CACHE && !STATS) {
                const uint4* cp = xcache + (size_t)(cid + 1) * 1024;
                #pragma unroll
                for (int q = 0; q < 4; ++q) cvN[q] = cp[q * 256 + t];
            } else {
                load_x(inp, b, n0 + 32, tok_s, seg8, ldN);
            }
        }
        __builtin_amdgcn_sched_barrier(0);

        // ---- iter0 cache mode: copy current xb image to ws ----
        if (CACHE && STATS) {
            uint4* cp = xcache + (size_t)cid * 1024;
            #pragma unroll
            for (int q = 0; q < 4; ++q)
                cp[q * 256 + t] = *(const uint4*)(xbB + (q * 4 + w) * 1040 + l * 16);
        }

        // ---- S = X(s) * W''^T ----
        f32x4 accS = (f32x4){0.f, 0.f, 0.f, 0.f};
        __builtin_amdgcn_s_setprio(1);
        #pragma unroll
        for (int kk = 0; kk < 8; ++kk) {
            s16x8 af = *(const s16x8*)(xbB + (kk * 2 + (g >> 1)) * 1040 +
                                       (Mt * 16 + li) * 32 + (g & 1) * 16);
            s16x8 bf = *(const s16x8*)(wlB + hqB * 512 + (((kk * 4 + g) ^ (hqB & 7)) * 16));
            accS = __builtin_amdgcn_mfma_f32_16x16x32_bf16(af, bf, accS, 0, 0, 0);
        }
        __builtin_amdgcn_s_setprio(0);

        // ---- logits + merged-barrier joint softmax over 32 hq ----
        float lg[4], rsv[4], rmv[4], mh[4], ex[4], aa[4];
        #pragma unroll
        for (int r = 0; r < 4; ++r) {
            int tokr = Mt * 16 + g * 4 + r;
            if (CACHE) {
                rmv[r] = stats[sidx][tokr];
                lg[r] = accS[r] - rmv[r] * c1r + c0r;
            } else {
                rsv[r] = stats[sidx][tokr];
                rmv[r] = stats[sidx][32 + tokr];
                lg[r] = fmaf(rsv[r], accS[r], fmaf(-rmv[r], c1r, c0r));
            }
        }
        #pragma unroll
        for (int r = 0; r < 4; ++r) {
            float v = lg[r];
            v = fmaxf(v, __shfl_xor(v, 1, 64));
            v = fmaxf(v, __shfl_xor(v, 2, 64));
            v = fmaxf(v, __shfl_xor(v, 4, 64));
            v = fmaxf(v, __shfl_xor(v, 8, 64));
            mh[r] = v;
            ex[r] = exp2f(lg[r] - v);
            float s = ex[r];
            s += __shfl_xor(s, 1, 64);
            s += __shfl_xor(s, 2, 64);
            s += __shfl_xor(s, 4, 64);
            s += __shfl_xor(s, 8, 64);
            if (li == 0) {
                int tokr = Mt * 16 + g * 4 + r;
                redm[tokr * 2 + Nt] = v;
                reds[tokr * 2 + Nt] = s;
            }
        }
        __syncthreads();   // B
        #pragma unroll
        for (int r = 0; r < 4; ++r) {
            int tokr = Mt * 16 + g * 4 + r;
            float m0 = redm[tokr * 2], m1 = redm[tokr * 2 + 1];
            float mx = fmaxf(m0, m1);
            float tot = reds[tokr * 2] * exp2f(m0 - mx) + reds[tokr * 2 + 1] * exp2f(m1 - mx);
            aa[r] = ex[r] * (exp2f(mh[r] - mx) / tot);
            A0acc += aa[r];
            A1acc = fmaf(aa[r], rmv[r], A1acc);
        }
        {
            uint2 pw;
            if (CACHE) {
                pw.x = pk2(aa[0], aa[1]);
                pw.y = pk2(aa[2], aa[3]);
            } else {
                pw.x = pk2(aa[0] * rsv[0], aa[1] * rsv[1]);
                pw.y = pk2(aa[2] * rsv[2], aa[3] * rsv[3]);
            }
            int tokb = Mt * 16 + g * 4;
            int slot = (tokb >> 3) ^ ((hqB >> 1) & 3);
            *(uint2*)(ptB + hqB * 64 + slot * 16 + (tokb & 7) * 2) = pw;
        }
        __syncthreads();   // D: P ready

        if (WVIS) {
            int tk = t >> 3, q = t & 7;
            float sv = 0.f;
            #pragma unroll
            for (int h = 0; h < 4; ++h) {
                int hq = h * 8 + q;
                int slot = (tk >> 3) ^ ((hq >> 1) & 3);
                sv += bf2f(*(const unsigned short*)(ptB + hq * 64 + slot * 16 + (tk & 7) * 2));
            }
            float vv = CACHE ? sv : sv / stats[sidx][tk];
            size_t o = ((size_t)b * NKV + n0 + tk) * 8 + q;
            out_vis[o] = vv; out_temp[o] = vv;
        }

        // ---- next-chunk stats (registers/LDS, no xb touch) ----
        float rsN = 1.f;
        if (ci < NC - 1) {
            if (STATS) {
                rsN = calc_stats(ldN, &stats[nxt][0], rs_g, rm_g, b, n0 + 32, tok_s, seg8, CACHE);
            } else if (!CACHE) {
                if (t < 32) stats[nxt][t] = rs_g[b * 4096 + n0 + 32 + t];
                else if (t < 64) stats[nxt][t] = rm_g[b * 4096 + n0 + 32 + t - 32];
            }
        }

        // ---- V += P^T(A) * X(B) via tr-reads ----
        {
            s16x8 pa = *(const s16x8*)(ptB + hqA * 64 + ((g ^ ((hqA >> 1) & 3)) * 16));
            unsigned abase = xbase + g * 256 + li * 8;
            v2i t0a = tr_read(abase + (ntb + 0) * 1040);
            v2i t0b = tr_read(abase + (ntb + 0) * 1040 + 128);
            v2i t1a = tr_read(abase + (ntb + 1) * 1040);
            v2i t1b = tr_read(abase + (ntb + 1) * 1040 + 128);
            v2i t2a = tr_read(abase + (ntb + 2) * 1040);
            v2i t2b = tr_read(abase + (ntb + 2) * 1040 + 128);
            v2i t3a = tr_read(abase + (ntb + 3) * 1040);
            v2i t3b = tr_read(abase + (ntb + 3) * 1040 + 128);
            asm volatile("s_waitcnt lgkmcnt(0)" ::: "memory");
            __builtin_amdgcn_sched_barrier(0);
            __builtin_amdgcn_s_setprio(1);
            av[0] = __builtin_amdgcn_mfma_f32_16x16x32_bf16(pa, mk_frag(t0a, t0b), av[0], 0, 0, 0);
            av[1] = __builtin_amdgcn_mfma_f32_16x16x32_bf16(pa, mk_frag(t1a, t1b), av[1], 0, 0, 0);
            av[2] = __builtin_amdgcn_mfma_f32_16x16x32_bf16(pa, mk_frag(t2a, t2b), av[2], 0, 0, 0);
            av[3] = __builtin_amdgcn_mfma_f32_16x16x32_bf16(pa, mk_frag(t3a, t3b), av[3], 0, 0, 0);
            __builtin_amdgcn_s_setprio(0);
            v2i t4a = tr_read(abase + (ntb + 4) * 1040);
            v2i t4b = tr_read(abase + (ntb + 4) * 1040 + 128);
            v2i t5a = tr_read(abase + (ntb + 5) * 1040);
            v2i t5b = tr_read(abase + (ntb + 5) * 1040 + 128);
            v2i t6a = tr_read(abase + (ntb + 6) * 1040);
            v2i t6b = tr_read(abase + (ntb + 6) * 1040 + 128);
            v2i t7a = tr_read(abase + (ntb + 7) * 1040);
            v2i t7b = tr_read(abase + (ntb + 7) * 1040 + 128);
            asm volatile("s_waitcnt lgkmcnt(0)" ::: "memory");
            __builtin_amdgcn_sched_barrier(0);
            __builtin_amdgcn_s_setprio(1);
            av[4] = __builtin_amdgcn_mfma_f32_16x16x32_bf16(pa, mk_frag(t4a, t4b), av[4], 0, 0, 0);
            av[5] = __builtin_amdgcn_mfma_f32_16x16x32_bf16(pa, mk_frag(t5a, t5b), av[5], 0, 0, 0);
            av[6] = __builtin_amdgcn_mfma_f32_16x16x32_bf16(pa, mk_frag(t6a, t6b), av[6], 0, 0, 0);
            av[7] = __builtin_amdgcn_mfma_f32_16x16x32_bf16(pa, mk_frag(t7a, t7b), av[7], 0, 0, 0);
            __builtin_amdgcn_s_setprio(0);
        }
        __syncthreads();   // E: all xb/pt reads complete

        // ---- stage next chunk into xb; A barrier ----
        if (ci < NC - 1) {
            if (CACHE && !STATS) {
                #pragma unroll
                for (int q = 0; q < 4; ++q)
                    *(uint4*)(xbB + (q * 4 + w) * 1040 + l * 16) = cvN[q];
            } else {
                pack_x(ldN, xbB, tok_s, seg8, CACHE ? rsN : 1.f);
            }
            __syncthreads();   // A
        }
    }

    // ---- epilogue: A0/A1 partials (no atomics), V bf16 partial stores ----
    A0acc += __shfl_xor(A0acc, 16, 64); A0acc += __shfl_xor(A0acc, 32, 64);
    A1acc += __shfl_xor(A1acc, 16, 64); A1acc += __shfl_xor(A1acc, 32, 64);
    const size_t blk = (size_t)b * KBMAX + kb;
    if (g == 0) {
        apart[blk * 128 + Mt * 64 + hqB] = A0acc;
        apart[blk * 128 + Mt * 64 + 32 + hqB] = A1acc;
    }
    {
        #pragma unroll
        for (int r = 0; r < 4; ++r) {
            int hq = MtV * 16 + g * 4 + r;
            unsigned* vp = vpart + (blk * 32 + hq) * 128 + li;
            #pragma unroll
            for (int ip = 0; ip < 4; ++ip) {
                unsigned u = pk2(av[2 * ip][r], av[2 * ip + 1][r]);
                int jp = (ntb >> 1) + ip;
                vp[jp * 16] = u;
            }
        }
    }
}

// ---------------------------------------------------------------------------
// V + A reduction: grid (32 b, 16). V rows 2/block; y==0 also reduces apart.
template<int KBMAX>
__global__ __launch_bounds__(256) void k_vred(
    const unsigned* __restrict__ vpart, const float* __restrict__ apart,
    float* __restrict__ V_g, float* __restrict__ A0_g, float* __restrict__ A1_g)
{
    const int t = threadIdx.x;
    const int b = blockIdx.x;
    const int hq = blockIdx.y * 2 + (t >> 7);
    const int tl = t & 127;
    const unsigned* p = vpart + ((size_t)(b * KBMAX) * 32 + hq) * 128 + tl;
    float lo = 0.f, hi = 0.f;
    #pragma unroll 8
    for (int kb = 0; kb < KBMAX; ++kb) {
        unsigned u = p[(size_t)kb * 4096];
        lo += bflo(u); hi += bfhi(u);
    }
    const int jp = tl >> 4, li = tl & 15;
    float* vo = V_g + ((size_t)b * 32 + hq) * 256 + jp * 32 + li;
    vo[0]  = lo;
    vo[16] = hi;

    if (blockIdx.y == 0 && t < 64) {
        float s = 0.f;
        const float* ap = apart + (size_t)(b * KBMAX) * 128 + t;
        #pragma unroll 8
        for (int kb = 0; kb < KBMAX; ++kb)
            s += ap[(size_t)kb * 128] + ap[(size_t)kb * 128 + 64];
        if (t < 32) A0_g[b * 32 + t] = s;
        else        A1_g[b * 32 + t - 32] = s;
    }
}

// ---------------------------------------------------------------------------
// gx | gh GEMMs. grid (6, 64). chunk-0 blocks zero slot_nxt (+ out_slots last iter).
__global__ __launch_bounds__(256) void k_gates(
    const float* __restrict__ V_g, const float* __restrict__ A0_g,
    const float* __restrict__ A1_g,
    const float* __restrict__ g_in, const float* __restrict__ b_in,
    const float* __restrict__ slot_cur,
    const unsigned* __restrict__ WfT2, const unsigned* __restrict__ WhhT2,
    float* __restrict__ gxh, float* __restrict__ slot_nxt,
    float* __restrict__ out_slots)
{
    __shared__ __align__(16) float aT[1024 * 4];
    const int t = threadIdx.x;
    const int rg = blockIdx.y;
    const int chunk = blockIdx.x;
    const int row0 = rg * 4;
    float acc0 = 0.f, acc1 = 0.f, acc2 = 0.f, acc3 = 0.f;

    if (chunk == 0) {
        #pragma unroll
        for (int rr = 0; rr < 4; ++rr) {
            slot_nxt[(size_t)(row0 + rr) * 256 + t] = 0.f;
            if (out_slots) out_slots[(size_t)(row0 + rr) * 256 + t] = 0.f;
        }
    }

    if (chunk < 3) {
        const int b = rg >> 1, qi0 = (rg & 1) * 4;
        const float gt = g_in[t], bt = b_in[t];
        #pragma unroll
        for (int kk = 0; kk < 4; ++kk) {
            float4 y4;
            #pragma unroll
            for (int rr = 0; rr < 4; ++rr) {
                int hq = kk * 8 + qi0 + rr;
                float A0 = A0_g[b * 32 + hq], A1 = A1_g[b * 32 + hq];
                float den = A0 + EPSR * (float)NKV;
                float vv = V_g[((size_t)b * 32 + hq) * 256 + t];
                float yv = (gt * (vv - A1) + bt * A0) / den;
                ((float*)&y4)[rr] = yv;
            }
            *(float4*)(aT + (kk * 256 + t) * 4) = y4;
        }
        __syncthreads();
        const unsigned* wp = WfT2 + chunk * 256 + t;
        #pragma unroll 4
        for (int k2 = 0; k2 < 512; ++k2) {
            unsigned wv = wp[(size_t)k2 * 768];
            float w0 = bflo(wv), w1 = bfhi(wv);
            float4 a0 = *(const float4*)(aT + 8 * k2);
            float4 a1 = *(const float4*)(aT + 8 * k2 + 4);
            acc0 = fmaf(a0.x, w0, acc0); acc0 = fmaf(a1.x, w1, acc0);
            acc1 = fmaf(a0.y, w0, acc1); acc1 = fmaf(a1.y, w1, acc1);
            acc2 = fmaf(a0.z, w0, acc2); acc2 = fmaf(a1.z, w1, acc2);
            acc3 = fmaf(a0.w, w0, acc3); acc3 = fmaf(a1.w, w1, acc3);
        }
        float* go = gxh + (size_t)row0 * 1536 + chunk * 256 + t;
        go[0] = acc0; go[1536] = acc1; go[3072] = acc2; go[4608] = acc3;
    } else {
        const int gc = chunk - 3;
        {
            float4 y4;
            #pragma unroll
            for (int rr = 0; rr < 4; ++rr)
                ((float*)&y4)[rr] = slot_cur[(size_t)(row0 + rr) * 256 + t];
            *(float4*)(aT + t * 4) = y4;
        }
        __syncthreads();
        const unsigned* wp = WhhT2 + gc * 256 + t;
        #pragma unroll 4
        for (int k2 = 0; k2 < 128; ++k2) {
            unsigned wv = wp[(size_t)k2 * 768];
            float w0 = bflo(wv), w1 = bfhi(wv);
            float4 a0 = *(const float4*)(aT + 8 * k2);
            float4 a1 = *(const float4*)(aT + 8 * k2 + 4);
            acc0 = fmaf(a0.x, w0, acc0); acc0 = fmaf(a1.x, w1, acc0);
            acc1 = fmaf(a0.y, w0, acc1); acc1 = fmaf(a1.y, w1, acc1);
            acc2 = fmaf(a0.z, w0, acc2); acc2 = fmaf(a1.z, w1, acc2);
            acc3 = fmaf(a0.w, w0, acc3); acc3 = fmaf(a1.w, w1, acc3);
        }
        float* go = gxh + (size_t)row0 * 1536 + 768 + gc * 256 + t;
        go[0] = acc0; go[1536] = acc1; go[3072] = acc2; go[4608] = acc3;
    }
}

// ---------------------------------------------------------------------------
// Fused GRU elementwise + LN + MLP(W1,relu,W2) with h1 in LDS. grid (4, 64).
__global__ __launch_bounds__(256) void k_mlp(
    const float* __restrict__ gxh, const float* __restrict__ slot_cur,
    const float* __restrict__ bih, const float* __restrict__ bhh,
    const float* __restrict__ gm, const float* __restrict__ bm,
    const unsigned* __restrict__ W1T2, const float* __restrict__ b1,
    const unsigned* __restrict__ W2T2, const float* __restrict__ b2,
    float* __restrict__ slot_nxt, float* __restrict__ out_slots)
{
    __shared__ __align__(16) float mT[1024];
    __shared__ float sm_l[4][256];
    __shared__ float h1_l[4][256];
    __shared__ float lnst[8];
    const int t = threadIdx.x;
    const int rg = blockIdx.y, chunk = blockIdx.x;
    const int row0 = rg * 4;
    const int lane = t & 63, w = t >> 6;

    const float bi0 = bih[t], bi1 = bih[256 + t], bi2 = bih[512 + t];
    const float bh0 = bhh[t], bh1 = bhh[256 + t], bh2 = bhh[512 + t];
    float smid[4];
    #pragma unroll
    for (int rr = 0; rr < 4; ++rr) {
        const float* gr = gxh + (size_t)(row0 + rr) * 1536;
        float gx0 = gr[t], gx1 = gr[256 + t], gx2 = gr[512 + t];
        float gh0 = gr[768 + t], gh1 = gr[1024 + t], gh2 = gr[1280 + t];
        float spv = slot_cur[(size_t)(row0 + rr) * 256 + t];
        float r = 1.f / (1.f + __expf(-(gx0 + bi0 + gh0 + bh0)));
        float z = 1.f / (1.f + __expf(-(gx1 + bi1 + gh1 + bh1)));
        float n = tanhf(gx2 + bi2 + r * (gh2 + bh2));
        smid[rr] = (1.f - z) * n + z * spv;
        sm_l[rr][t] = smid[rr];
    }
    __syncthreads();
    {
        float4 v = *(const float4*)(&sm_l[w][lane * 4]);
        float s0 = v.x + v.y + v.z + v.w;
        float s1 = v.x * v.x + v.y * v.y + v.z * v.z + v.w * v.w;
        #pragma unroll
        for (int o = 32; o >= 1; o >>= 1) { s0 += __shfl_xor(s0, o, 64); s1 += __shfl_xor(s1, o, 64); }
        if (lane == 0) {
            float mu = s0 * (1.f / 256.f);
            lnst[w * 2] = mu;
            lnst[w * 2 + 1] = rsqrtf(s1 * (1.f / 256.f) - mu * mu + 1e-5f);
        }
    }
    __syncthreads();
    {
        const float gmt = gm[t], bmt = bm[t];
        float4 m4;
        #pragma unroll
        for (int rr = 0; rr < 4; ++rr)
            ((float*)&m4)[rr] = (smid[rr] - lnst[rr * 2]) * lnst[rr * 2 + 1] * gmt + bmt;
        *(float4*)(mT + t * 4) = m4;
    }
    __syncthreads();

    {
        float acc0 = 0.f, acc1 = 0.f, acc2 = 0.f, acc3 = 0.f;
        const unsigned* wp = W1T2 + chunk * 256 + t;
        #pragma unroll 4
        for (int k2 = 0; k2 < 128; ++k2) {
            unsigned wv = wp[(size_t)k2 * 1024];
            float w0 = bflo(wv), w1 = bfhi(wv);
            float4 a0 = *(const float4*)(mT + 8 * k2);
            float4 a1 = *(const float4*)(mT + 8 * k2 + 4);
            acc0 = fmaf(a0.x, w0, acc0); acc0 = fmaf(a1.x, w1, acc0);
            acc1 = fmaf(a0.y, w0, acc1); acc1 = fmaf(a1.y, w1, acc1);
            acc2 = fmaf(a0.z, w0, acc2); acc2 = fmaf(a1.z, w1, acc2);
            acc3 = fmaf(a0.w, w0, acc3); acc3 = fmaf(a1.w, w1, acc3);
        }
        const float b1t = b1[chunk * 256 + t];
        h1_l[0][t] = fmaxf(acc0 + b1t, 0.f);
        h1_l[1][t] = fmaxf(acc1 + b1t, 0.f);
        h1_l[2][t] = fmaxf(acc2 + b1t, 0.f);
        h1_l[3][t] = fmaxf(acc3 + b1t, 0.f);
    }
    __syncthreads();

    {
        float o0 = 0.f, o1 = 0.f, o2 = 0.f, o3 = 0.f;
        const unsigned* wp = W2T2 + (size_t)(chunk * 128) * 256 + t;
        #pragma unroll 4
        for (int k2 = 0; k2 < 128; ++k2) {
            unsigned wv = wp[(size_t)k2 * 256];
            float w0 = bflo(wv), w1 = bfhi(wv);
            float a00 = h1_l[0][2 * k2], a01 = h1_l[0][2 * k2 + 1];
            float a10 = h1_l[1][2 * k2], a11 = h1_l[1][2 * k2 + 1];
            float a20 = h1_l[2][2 * k2], a21 = h1_l[2][2 * k2 + 1];
            float a30 = h1_l[3][2 * k2], a31 = h1_l[3][2 * k2 + 1];
            o0 = fmaf(a00, w0, o0); o0 = fmaf(a01, w1, o0);
            o1 = fmaf(a10, w0, o1); o1 = fmaf(a11, w1, o1);
            o2 = fmaf(a20, w0, o2); o2 = fmaf(a21, w1, o2);
            o3 = fmaf(a30, w0, o3); o3 = fmaf(a31, w1, o3);
        }
        const float b2t = b2[t];
        float p0 = o0 + ((chunk == 0) ? smid[0] + b2t : 0.f);
        float p1 = o1 + ((chunk == 0) ? smid[1] + b2t : 0.f);
        float p2 = o2 + ((chunk == 0) ? smid[2] + b2t : 0.f);
        float p3 = o3 + ((chunk == 0) ? smid[3] + b2t : 0.f);
        atomicAdd(slot_nxt + (size_t)(row0 + 0) * 256 + t, p0);
        atomicAdd(slot_nxt + (size_t)(row0 + 1) * 256 + t, p1);
        atomicAdd(slot_nxt + (size_t)(row0 + 2) * 256 + t, p2);
        atomicAdd(slot_nxt + (size_t)(row0 + 3) * 256 + t, p3);
        if (out_slots) {
            atomicAdd(out_slots + (size_t)(row0 + 0) * 256 + t, p0);
            atomicAdd(out_slots + (size_t)(row0 + 1) * 256 + t, p1);
            atomicAdd(out_slots + (size_t)(row0 + 2) * 256 + t, p2);
            atomicAdd(out_slots + (size_t)(row0 + 3) * 256 + t, p3);
        }
    }
}

// ---------------------------------------------------------------------------
extern "C" void kernel_launch(void* const* d_in, const int* in_sizes, int n_in,
                              void* d_out, int out_size, void* d_ws, size_t ws_size,
                              hipStream_t stream) {
    const float* inp     = (const float*)d_in[0];
    const float* slots0  = (const float*)d_in[1];
    const float* ln_in_g = (const float*)d_in[2];
    const float* ln_in_b = (const float*)d_in[3];
    const float* ln_s_g  = (const float*)d_in[4];
    const float* ln_s_b  = (const float*)d_in[5];
    const float* ln_m_g  = (const float*)d_in[6];
    const float* ln_m_b  = (const float*)d_in[7];
    const float* Wq  = (const float*)d_in[8];
    const float* Wk  = (const float*)d_in[9];
    const float* Wv  = (const float*)d_in[10];
    const float* Wih = (const float*)d_in[11];
    const float* Whh = (const float*)d_in[12];
    const float* bih = (const float*)d_in[13];
    const float* bhh = (const float*)d_in[14];
    const float* W1  = (const float*)d_in[15];
    const float* b1  = (const float*)d_in[16];
    const float* W2  = (const float*)d_in[17];
    const float* b2  = (const float*)d_in[18];

    float* ws = (float*)d_ws;
    float* V_g   = ws + WS_V;
    float* A0_g  = ws + WS_A0;
    float* A1_g  = ws + WS_A1;
    float* c0_g  = ws + WS_C0;
    float* c1_g  = ws + WS_C1;
    float* slotA = ws + WS_SLOTA;
    float* slotB = ws + WS_SLOTB;
    float* wqt   = ws + WS_WQT;
    float* gxh   = ws + WS_WPGXH;
    unsigned short* wp_bf = (unsigned short*)(ws + WS_WPGXH);
    unsigned* WfT2  = (unsigned*)(ws + WS_WFT);
    unsigned* WhhT2 = (unsigned*)(ws + WS_WHHT);
    unsigned* W1T2  = (unsigned*)(ws + WS_W1T);
    unsigned* W2T2  = (unsigned*)(ws + WS_W2T);
    float* rs_g  = ws + WS_RS;
    float* rm_g  = ws + WS_RM;
    unsigned* vpart = (unsigned*)(ws + WS_VPART);
    float* apart = ws + WS_APART;
    uint4* xcache = (uint4*)(ws + WS_XC);

    const int useCache = (ws_size >= WS_NEED_BYTE) ? 1 : 0;

    float* out_slots = (float*)d_out;
    float* out_vis   = out_slots + 32 * 8 * 256;
    float* out_temp  = out_vis + 32 * 4096 * 8;

    k_tr<<<dim3(8, 8), dim3(32, 8), 0, stream>>>(Wq, wqt, 256, 256);
    k_wfold<<<768, 256, 0, stream>>>(Wih, Wv, WfT2);
    k_trpack<<<128, 256, 0, stream>>>(Whh, WhhT2, 768, 256);
    k_trpack<<<128, 256, 0, stream>>>(W1, W1T2, 1024, 256);
    k_trpack<<<512, 256, 0, stream>>>(W2, W2T2, 256, 1024);
    k_copy<<<256, 256, 0, stream>>>(slots0, slotA, 65536);

    for (int it = 0; it < 3; ++it) {
        float* cur = (it & 1) ? slotB : slotA;
        float* nxt = (it & 1) ? slotA : slotB;
        k_prep<<<dim3(32, 4), 256, 0, stream>>>(cur, ln_s_g, ln_s_b, wqt, Wk,
                                                ln_in_g, ln_in_b, wp_bf, c0_g, c1_g);
        if (useCache) {
            if (it == 0)
                k_attn<2, 1, 1, 0><<<dim3(64, 32), 256, 0, stream>>>(
                    inp, wp_bf, c0_g, c1_g, vpart, apart, rs_g, rm_g, xcache, out_vis, out_temp);
            else if (it == 1)
                k_attn<2, 1, 0, 0><<<dim3(64, 32), 256, 0, stream>>>(
                    inp, wp_bf, c0_g, c1_g, vpart, apart, rs_g, rm_g, xcache, out_vis, out_temp);
            else
                k_attn<2, 1, 0, 1><<<dim3(64, 32), 256, 0, stream>>>(
                    inp, wp_bf, c0_g, c1_g, vpart, apart, rs_g, rm_g, xcache, out_vis, out_temp);
        } else {
            if (it == 0)
                k_attn<2, 0, 1, 0><<<dim3(64, 32), 256, 0, stream>>>(
                    inp, wp_bf, c0_g, c1_g, vpart, apart, rs_g, rm_g, xcache, out_vis, out_temp);
            else if (it == 1)
                k_attn<2, 0, 0, 0><<<dim3(64, 32), 256, 0, stream>>>(
                    inp, wp_bf, c0_g, c1_g, vpart, apart, rs_g, rm_g, xcache, out_vis, out_temp);
            else
                k_attn<2, 0, 0, 1><<<dim3(64, 32), 256, 0, stream>>>(
                    inp, wp_bf, c0_g, c1_g, vpart, apart, rs_g, rm_g, xcache, out_vis, out_temp);
        }
        k_vred<64><<<dim3(32, 16), 256, 0, stream>>>(vpart, apart, V_g, A0_g, A1_g);
        k_gates<<<dim3(6, 64), 256, 0, stream>>>(
            V_g, A0_g, A1_g, ln_in_g, ln_in_b, cur, WfT2, WhhT2, gxh, nxt,
            (it == 2) ? out_slots : nullptr);
        k_mlp<<<dim3(4, 64), 256, 0, stream>>>(
            gxh, cur, bih, bhh, ln_m_g, ln_m_b, W1T2, b1, W2T2, b2, nxt,
            (it == 2) ? out_slots : nullptr);
    }
}

// Round 13
// 446.310 us; speedup vs baseline: 1.0362x; 1.0362x over previous
//
#include <hip/hip_runtime.h>
#include <math.h>

// ---------------------------------------------------------------------------
// SlotAttention fused forward. MFMA (bf16) attention path.
//   xb holds RAW bf16 x (single buffer, 4 blocks/CU); register prefetch of
//   next chunk; pack after E barrier. logit = rs*dot(x,w'') - rm*c1 + c0.
//   IN-WAVE softmax: each wave computes BOTH hq-half S-tiles (16 MFMA) so the
//   full 32-hq row is in-register -> no cross-wave LDS reduce, no barrier B.
//   P = a*rs; rs/rm iteration-invariant (iter0 computes+stores, 1-2 load).
//   A0/A1: per-block partials (apart), V partials bf16 (vpart) -> k_vred.
//   GRU/MLP: gx = yflat @ Wfold^T; k_gates + fused k_mlp.
// ---------------------------------------------------------------------------

#define NKV   4096
#define DD    256
#define HQN   32
#define EPSR  1e-8f

// workspace layout (float offsets)
#define WS_V      0                     // 262144
#define WS_A0     262144                // 1024
#define WS_A1     263168                // 1024
#define WS_C0     264192                // 1024
#define WS_C1     265216                // 1024
#define WS_SLOTA  266240                // 65536
#define WS_SLOTB  331776                // 65536
#define WS_WQT    397312                // 65536 fp32 Wq^T
#define WS_WPGXH  462848                // 393216 (wp_bf 131072f | gxh [256][1536])
#define WS_WFT    856064                // 393216 uints: WfoldT2 [512][768]
#define WS_WHHT   1249280               // 98304 uints:  WhhT2   [128][768]
#define WS_W1T    1347584               // 131072 uints: W1T2    [128][1024]
#define WS_W2T    1478656               // 131072 uints: W2T2    [512][256]
#define WS_RS     1609728               // 131072 fp32 rs per token
#define WS_RM     1740800               // 131072 fp32 rm per token
#define WS_VPART  1871872               // 8388608 uints: Vpart bf16x2, 32MB
#define WS_APART  10260480              // 262144 fp32: apart[2048 blk][128]
// total ≈ 42 MB (proven available)

typedef float f32x4 __attribute__((ext_vector_type(4)));
typedef short s16x8 __attribute__((ext_vector_type(8)));
typedef int   v2i   __attribute__((ext_vector_type(2)));

__device__ __forceinline__ unsigned bfr(float f) {
    unsigned u = __float_as_uint(f);
    return (u + 0x7fffu + ((u >> 16) & 1u)) >> 16;
}
__device__ __forceinline__ unsigned pk2(float lo, float hi) {
    return bfr(lo) | (bfr(hi) << 16);
}
__device__ __forceinline__ float bf2f(unsigned short us) {
    return __uint_as_float((unsigned)us << 16);
}
__device__ __forceinline__ float bflo(unsigned u) { return __uint_as_float(u << 16); }
__device__ __forceinline__ float bfhi(unsigned u) { return __uint_as_float(u & 0xffff0000u); }

__device__ __forceinline__ v2i tr_read(unsigned addr) {
    v2i d;
    asm volatile("ds_read_b64_tr_b16 %0, %1" : "=v"(d) : "v"(addr));
    return d;
}
__device__ __forceinline__ s16x8 mk_frag(v2i a, v2i b) {
    union { int i[4]; s16x8 s; } u;
    u.i[0] = a.x; u.i[1] = a.y; u.i[2] = b.x; u.i[3] = b.y;
    return u.s;
}

__global__ __launch_bounds__(256) void k_copy(const float* __restrict__ in,
                                              float* __restrict__ out, int n) {
    int i = blockIdx.x * 256 + threadIdx.x;
    if (i < n) out[i] = in[i];
}

// generic 32x32 tiled fp32 transpose: in[R][C] -> out[C][R]
__global__ __launch_bounds__(256) void k_tr(const float* __restrict__ in,
                                            float* __restrict__ out, int R, int C) {
    __shared__ float tile[32][33];
    int bx = blockIdx.x * 32, by = blockIdx.y * 32;
    int x = bx + threadIdx.x;
    for (int k = 0; k < 32; k += 8) {
        int y = by + threadIdx.y + k;
        if (x < C && y < R) tile[threadIdx.y + k][threadIdx.x] = in[(size_t)y * C + x];
    }
    __syncthreads();
    int r = by + threadIdx.x;
    for (int k = 0; k < 32; k += 8) {
        int c = bx + threadIdx.y + k;
        if (c < C && r < R) out[(size_t)c * R + r] = tile[threadIdx.x][threadIdx.y + k];
    }
}

// ---------------------------------------------------------------------------
// Wfold: one block per output row c.
__global__ __launch_bounds__(256) void k_wfold(
    const float* __restrict__ Wih, const float* __restrict__ Wv,
    unsigned* __restrict__ WfT2)
{
    __shared__ float wr[256];
    const int c = blockIdx.x, t = threadIdx.x;
    wr[t] = Wih[(size_t)c * 256 + t];
    __syncthreads();
    const float2* wv2 = (const float2*)Wv;
    #pragma unroll
    for (int pp = 0; pp < 2; ++pp) {
        int P = pp * 256 + t;
        int h = P >> 7, p = P & 127;
        float f0 = 0.f, f1 = 0.f;
        #pragma unroll 8
        for (int d = 0; d < 64; ++d) {
            float a = wr[h * 64 + d];
            float2 v = wv2[(size_t)(h * 64 + d) * 128 + p];
            f0 = fmaf(a, v.x, f0); f1 = fmaf(a, v.y, f1);
        }
        WfT2[(size_t)P * 768 + c] = pk2(f0, f1);
    }
}

// transpose+pack: in fp32 [R][C] -> out uint [C/2][R]
__global__ __launch_bounds__(256) void k_trpack(
    const float* __restrict__ in, unsigned* __restrict__ out, int R, int C)
{
    const int c2 = blockIdx.x;
    const int t = threadIdx.x;
    for (int q = 0; q < R / 256; ++q) {
        int r = q * 256 + t;
        out[(size_t)c2 * R + r] = pk2(in[(size_t)r * C + 2 * c2],
                                      in[(size_t)r * C + 2 * c2 + 1]);
    }
}

// ---------------------------------------------------------------------------
// Merged slot prep: grid (32 b, 4 h).
__global__ __launch_bounds__(256) void k_prep(
    const float* __restrict__ slots, const float* __restrict__ g_s, const float* __restrict__ b_s,
    const float* __restrict__ wqt, const float* __restrict__ Wk,
    const float* __restrict__ g_in, const float* __restrict__ b_in,
    unsigned short* __restrict__ wp_bf, float* __restrict__ c0_g, float* __restrict__ c1_g)
{
    __shared__ float s_lds[2048];
    __shared__ float qs[512];
    __shared__ float redc[4096];
    const int t = threadIdx.x;
    const int b = blockIdx.x, h = blockIdx.y;
    const int lane = t & 63, w = t >> 6;
    const float LNS = 0.125f * 1.44269504f;

    for (int r = w; r < 8; r += 4) {
        const float4 v = ((const float4*)(slots + ((size_t)b * 8 + r) * 256))[lane];
        float s0 = v.x + v.y + v.z + v.w;
        float s1 = v.x * v.x + v.y * v.y + v.z * v.z + v.w * v.w;
        #pragma unroll
        for (int o = 32; o >= 1; o >>= 1) { s0 += __shfl_xor(s0, o, 64); s1 += __shfl_xor(s1, o, 64); }
        float m = s0 * (1.f / 256.f);
        float rs = rsqrtf(s1 * (1.f / 256.f) - m * m + 1e-5f);
        float4 gg = ((const float4*)g_s)[lane];
        float4 bb = ((const float4*)b_s)[lane];
        float4 nn;
        nn.x = (v.x - m) * rs * gg.x + bb.x;
        nn.y = (v.y - m) * rs * gg.y + bb.y;
        nn.z = (v.z - m) * rs * gg.z + bb.z;
        nn.w = (v.w - m) * rs * gg.w + bb.w;
        ((float4*)(s_lds + r * 256))[lane] = nn;
    }
    __syncthreads();

    {
        const int qi0 = t >> 6, d = t & 63;
        float a0 = 0.f, a1 = 0.f;
        #pragma unroll 8
        for (int j = 0; j < 256; ++j) {
            float wv = wqt[j * 256 + h * 64 + d];
            a0 = fmaf(s_lds[qi0 * 256 + j], wv, a0);
            a1 = fmaf(s_lds[(qi0 + 4) * 256 + j], wv, a1);
        }
        qs[qi0 * 64 + d] = a0;
        qs[(qi0 + 4) * 64 + d] = a1;
    }
    __syncthreads();

    float a2[8];
    #pragma unroll
    for (int qi = 0; qi < 8; ++qi) a2[qi] = 0.f;
    #pragma unroll 4
    for (int d = 0; d < 64; ++d) {
        float wv = Wk[(size_t)(h * 64 + d) * 256 + t];
        #pragma unroll
        for (int qi = 0; qi < 8; ++qi) a2[qi] = fmaf(qs[qi * 64 + d], wv, a2[qi]);
    }
    const float gv = g_in[t], bv = b_in[t];
    #pragma unroll
    for (int qi = 0; qi < 8; ++qi) {
        float kv = LNS * a2[qi];
        float we = kv * gv;
        wp_bf[((size_t)b * HQN + h * 8 + qi) * 256 + t] = (unsigned short)bfr(we);
        redc[qi * 256 + t] = we;
        redc[2048 + qi * 256 + t] = kv * bv;
    }
    __syncthreads();
    #pragma unroll
    for (int rep = 0; rep < 2; ++rep) {
        int r = w * 2 + rep;
        float sv1 = redc[r * 256 + lane] + redc[r * 256 + 64 + lane] +
                    redc[r * 256 + 128 + lane] + redc[r * 256 + 192 + lane];
        float sv0 = redc[2048 + r * 256 + lane] + redc[2048 + r * 256 + 64 + lane] +
                    redc[2048 + r * 256 + 128 + lane] + redc[2048 + r * 256 + 192 + lane];
        #pragma unroll
        for (int o = 32; o >= 1; o >>= 1) {
            sv1 += __shfl_xor(sv1, o, 64);
            sv0 += __shfl_xor(sv0, o, 64);
        }
        if (lane == 0) {
            c1_g[b * 32 + h * 8 + r] = sv1;
            c0_g[b * 32 + h * 8 + r] = sv0;
        }
    }
}

// ---------------------------------------------------------------------------
// k_attn helpers
__device__ __forceinline__ void load_x(const float* __restrict__ inp, int b, int n0,
                                       int tok_s, int seg8, float4* ld) {
    const float4* row4 = (const float4*)(inp + ((size_t)b * NKV + n0 + tok_s) * 256);
    #pragma unroll
    for (int u = 0; u < 8; ++u) ld[u] = row4[(u >> 2) * 32 + seg8 * 4 + (u & 3)];
}

__device__ __forceinline__ void pack_x(const float4* ld, char* dst, int tok_s, int seg8) {
    #pragma unroll
    for (int c = 0; c < 2; ++c) {
        int nt = seg8 + 8 * c;
        #pragma unroll
        for (int h = 0; h < 2; ++h) {
            float4 fa = ld[c * 4 + h * 2], fb = ld[c * 4 + h * 2 + 1];
            uint4 pk;
            pk.x = pk2(fa.x, fa.y); pk.y = pk2(fa.z, fa.w);
            pk.z = pk2(fb.x, fb.y); pk.w = pk2(fb.z, fb.w);
            *(uint4*)(dst + nt * 1040 + tok_s * 32 + h * 16) = pk;
        }
    }
}

__device__ __forceinline__ void calc_stats(const float4* ld, float* sb,
                                           float* __restrict__ rs_g, float* __restrict__ rm_g,
                                           int b, int n0, int tok_s, int seg8) {
    float s0 = 0.f, s1 = 0.f;
    #pragma unroll
    for (int u = 0; u < 8; ++u) {
        float4 v = ld[u];
        s0 += v.x + v.y + v.z + v.w;
        s1 = fmaf(v.x, v.x, s1); s1 = fmaf(v.y, v.y, s1);
        s1 = fmaf(v.z, v.z, s1); s1 = fmaf(v.w, v.w, s1);
    }
    s0 += __shfl_xor(s0, 1, 64); s1 += __shfl_xor(s1, 1, 64);
    s0 += __shfl_xor(s0, 2, 64); s1 += __shfl_xor(s1, 2, 64);
    s0 += __shfl_xor(s0, 4, 64); s1 += __shfl_xor(s1, 4, 64);
    float m  = s0 * (1.f / 256.f);
    float rs = rsqrtf(s1 * (1.f / 256.f) - m * m + 1e-5f);
    if (seg8 == 0) {
        sb[tok_s] = rs;
        sb[32 + tok_s] = rs * m;
        rs_g[b * 4096 + n0 + tok_s] = rs;
        rm_g[b * 4096 + n0 + tok_s] = rs * m;
    }
}

// ---------------------------------------------------------------------------
// Main fused MFMA pass. grid (64, 32): NC=2 chunks of 32 tokens per block.
// In-wave softmax: each wave computes both hq-half S-tiles (16 MFMA), full
// 32-hq row in registers -> 3 barriers/chunk, no LDS softmax reduce.
template<int NC, int STATS, int WVIS>
__global__ __launch_bounds__(256) void k_attn(
    const float* __restrict__ inp, const unsigned short* __restrict__ wp_bf,
    const float* __restrict__ c0_g, const float* __restrict__ c1_g,
    unsigned* __restrict__ vpart, float* __restrict__ apart,
    float* __restrict__ rs_g, float* __restrict__ rm_g,
    float* __restrict__ out_vis, float* __restrict__ out_temp)
{
    constexpr int KBMAX = 128 / NC;
    __shared__ unsigned short xb[8320];         // 16640 B single buffer
    __shared__ unsigned short wl[8192];         // [hq][k] swizzled
    __shared__ unsigned short pt[1024];         // [hq][tok] bf16 P (= a*rs)
    __shared__ float stats[2][64];              // [0..32): rs, [32..64): rm

    const int t = threadIdx.x;
    const int l = t & 63, w = t >> 6;
    const int g = l >> 4, li = l & 15;
    const int b = blockIdx.y, kb = blockIdx.x;

    char* xbB = (char*)xb;
    char* wlB = (char*)wl;
    char* ptB = (char*)pt;
    const int tok_s = t >> 3, seg8 = t & 7;
    const int cbase = kb * NC;

    // stage W'' into LDS (swizzled rows [hq][k])
    {
        const uint4* wp4 = (const uint4*)wp_bf + ((size_t)b * 8192 + (t >> 3) * 256 + (t & 7) * 32) / 8;
        const int hq = t >> 3, sg = t & 7;
        #pragma unroll
        for (int q = 0; q < 4; ++q) {
            uint4 v = wp4[q];
            *(uint4*)(wlB + hq * 512 + (((sg * 4 + q) ^ (hq & 7)) * 16)) = v;
        }
    }

    const int Mt = w & 1, Nt = w >> 1;
    const int hqB = Nt * 16 + li;               // P-write / A-epilogue hq
    const int hq0 = li, hq1 = 16 + li;          // both halves for S
    const float c0h0 = c0_g[b * 32 + hq0], c1h0 = c1_g[b * 32 + hq0];
    const float c0h1 = c0_g[b * 32 + hq1], c1h1 = c1_g[b * 32 + hq1];
    const int MtV = w >> 1, ntb = (w & 1) * 8;
    const int hqA = MtV * 16 + li;

    f32x4 av[8];
    #pragma unroll
    for (int u = 0; u < 8; ++u) av[u] = (f32x4){0.f, 0.f, 0.f, 0.f};
    float A0acc = 0.f, A1acc = 0.f;

    const unsigned xbase = (unsigned)(uintptr_t)xbB;

    // ---- prologue: chunk 0 ----
    {
        float4 ldA[8];
        load_x(inp, b, cbase * 32, tok_s, seg8, ldA);
        if (STATS) {
            calc_stats(ldA, &stats[0][0], rs_g, rm_g, b, cbase * 32, tok_s, seg8);
        } else {
            if (t < 32) stats[0][t] = rs_g[b * 4096 + cbase * 32 + t];
            else if (t < 64) stats[0][t] = rm_g[b * 4096 + cbase * 32 + t - 32];
        }
        pack_x(ldA, xbB, tok_s, seg8);
    }
    __syncthreads();   // A

    #pragma unroll
    for (int ci = 0; ci < NC; ++ci) {
        const int cur = ci & 1, nxt = cur ^ 1;
        const int n0 = (cbase + ci) * 32;

        // ---- issue next-chunk loads ----
        float4 ldN[8];
        if (ci < NC - 1) load_x(inp, b, n0 + 32, tok_s, seg8, ldN);
        __builtin_amdgcn_sched_barrier(0);

        // ---- S: both hq-half tiles per wave (full 32-hq row in-register) ----
        f32x4 accS0 = (f32x4){0.f, 0.f, 0.f, 0.f};
        f32x4 accS1 = (f32x4){0.f, 0.f, 0.f, 0.f};
        __builtin_amdgcn_s_setprio(1);
        #pragma unroll
        for (int kk = 0; kk < 8; ++kk) {
            s16x8 af = *(const s16x8*)(xbB + (kk * 2 + (g >> 1)) * 1040 +
                                       (Mt * 16 + li) * 32 + (g & 1) * 16);
            s16x8 bf0 = *(const s16x8*)(wlB + hq0 * 512 + (((kk * 4 + g) ^ (hq0 & 7)) * 16));
            s16x8 bf1 = *(const s16x8*)(wlB + hq1 * 512 + (((kk * 4 + g) ^ (hq1 & 7)) * 16));
            accS0 = __builtin_amdgcn_mfma_f32_16x16x32_bf16(af, bf0, accS0, 0, 0, 0);
            accS1 = __builtin_amdgcn_mfma_f32_16x16x32_bf16(af, bf1, accS1, 0, 0, 0);
        }
        __builtin_amdgcn_s_setprio(0);

        // ---- logits + fully in-wave joint softmax over 32 hq ----
        float aaW[4], rsv[4], rmv[4];
        #pragma unroll
        for (int r = 0; r < 4; ++r) {
            int tokr = Mt * 16 + g * 4 + r;
            rsv[r] = stats[cur][tokr];
            rmv[r] = stats[cur][32 + tokr];
            float lg0 = fmaf(rsv[r], accS0[r], fmaf(-rmv[r], c1h0, c0h0));
            float lg1 = fmaf(rsv[r], accS1[r], fmaf(-rmv[r], c1h1, c0h1));
            float v = fmaxf(lg0, lg1);
            v = fmaxf(v, __shfl_xor(v, 1, 64));
            v = fmaxf(v, __shfl_xor(v, 2, 64));
            v = fmaxf(v, __shfl_xor(v, 4, 64));
            v = fmaxf(v, __shfl_xor(v, 8, 64));
            float ex0 = exp2f(lg0 - v);
            float ex1 = exp2f(lg1 - v);
            float s = ex0 + ex1;
            s += __shfl_xor(s, 1, 64);
            s += __shfl_xor(s, 2, 64);
            s += __shfl_xor(s, 4, 64);
            s += __shfl_xor(s, 8, 64);
            float inv = 1.f / s;
            float aw = (Nt ? ex1 : ex0) * inv;   // this wave's quadrant value
            A0acc += aw;
            A1acc = fmaf(aw, rmv[r], A1acc);
            aaW[r] = aw * rsv[r];                // P = a*rs
        }
        {
            uint2 pw;
            pw.x = pk2(aaW[0], aaW[1]);
            pw.y = pk2(aaW[2], aaW[3]);
            int tokb = Mt * 16 + g * 4;
            int slot = (tokb >> 3) ^ ((hqB >> 1) & 3);
            *(uint2*)(ptB + hqB * 64 + slot * 16 + (tokb & 7) * 2) = pw;
        }
        __syncthreads();   // D: P ready

        if (WVIS) {
            int tk = t >> 3, q = t & 7;
            float sv = 0.f;
            #pragma unroll
            for (int h = 0; h < 4; ++h) {
                int hq = h * 8 + q;
                int slot = (tk >> 3) ^ ((hq >> 1) & 3);
                sv += bf2f(*(const unsigned short*)(ptB + hq * 64 + slot * 16 + (tk & 7) * 2));
            }
            float vv = sv / stats[cur][tk];
            size_t o = ((size_t)b * NKV + n0 + tk) * 8 + q;
            out_vis[o] = vv; out_temp[o] = vv;
        }

        // ---- next-chunk stats (no xb touch) ----
        if (ci < NC - 1) {
            if (STATS) {
                calc_stats(ldN, &stats[nxt][0], rs_g, rm_g, b, n0 + 32, tok_s, seg8);
            } else {
                if (t < 32) stats[nxt][t] = rs_g[b * 4096 + n0 + 32 + t];
                else if (t < 64) stats[nxt][t] = rm_g[b * 4096 + n0 + 32 + t - 32];
            }
        }

        // ---- V += P^T(A) * X(B) via tr-reads ----
        {
            s16x8 pa = *(const s16x8*)(ptB + hqA * 64 + ((g ^ ((hqA >> 1) & 3)) * 16));
            unsigned abase = xbase + g * 256 + li * 8;
            v2i t0a = tr_read(abase + (ntb + 0) * 1040);
            v2i t0b = tr_read(abase + (ntb + 0) * 1040 + 128);
            v2i t1a = tr_read(abase + (ntb + 1) * 1040);
            v2i t1b = tr_read(abase + (ntb + 1) * 1040 + 128);
            v2i t2a = tr_read(abase + (ntb + 2) * 1040);
            v2i t2b = tr_read(abase + (ntb + 2) * 1040 + 128);
            v2i t3a = tr_read(abase + (ntb + 3) * 1040);
            v2i t3b = tr_read(abase + (ntb + 3) * 1040 + 128);
            asm volatile("s_waitcnt lgkmcnt(0)" ::: "memory");
            __builtin_amdgcn_sched_barrier(0);
            __builtin_amdgcn_s_setprio(1);
            av[0] = __builtin_amdgcn_mfma_f32_16x16x32_bf16(pa, mk_frag(t0a, t0b), av[0], 0, 0, 0);
            av[1] = __builtin_amdgcn_mfma_f32_16x16x32_bf16(pa, mk_frag(t1a, t1b), av[1], 0, 0, 0);
            av[2] = __builtin_amdgcn_mfma_f32_16x16x32_bf16(pa, mk_frag(t2a, t2b), av[2], 0, 0, 0);
            av[3] = __builtin_amdgcn_mfma_f32_16x16x32_bf16(pa, mk_frag(t3a, t3b), av[3], 0, 0, 0);
            __builtin_amdgcn_s_setprio(0);
            v2i t4a = tr_read(abase + (ntb + 4) * 1040);
            v2i t4b = tr_read(abase + (ntb + 4) * 1040 + 128);
            v2i t5a = tr_read(abase + (ntb + 5) * 1040);
            v2i t5b = tr_read(abase + (ntb + 5) * 1040 + 128);
            v2i t6a = tr_read(abase + (ntb + 6) * 1040);
            v2i t6b = tr_read(abase + (ntb + 6) * 1040 + 128);
            v2i t7a = tr_read(abase + (ntb + 7) * 1040);
            v2i t7b = tr_read(abase + (ntb + 7) * 1040 + 128);
            asm volatile("s_waitcnt lgkmcnt(0)" ::: "memory");
            __builtin_amdgcn_sched_barrier(0);
            __builtin_amdgcn_s_setprio(1);
            av[4] = __builtin_amdgcn_mfma_f32_16x16x32_bf16(pa, mk_frag(t4a, t4b), av[4], 0, 0, 0);
            av[5] = __builtin_amdgcn_mfma_f32_16x16x32_bf16(pa, mk_frag(t5a, t5b), av[5], 0, 0, 0);
            av[6] = __builtin_amdgcn_mfma_f32_16x16x32_bf16(pa, mk_frag(t6a, t6b), av[6], 0, 0, 0);
            av[7] = __builtin_amdgcn_mfma_f32_16x16x32_bf16(pa, mk_frag(t7a, t7b), av[7], 0, 0, 0);
            __builtin_amdgcn_s_setprio(0);
        }
        __syncthreads();   // E: all xb/pt reads complete

        // ---- pack next chunk into xb; A barrier ----
        if (ci < NC - 1) {
            pack_x(ldN, xbB, tok_s, seg8);
            __syncthreads();   // A
        }
    }

    // ---- epilogue: A0/A1 partials (no atomics), V bf16 partial stores ----
    A0acc += __shfl_xor(A0acc, 16, 64); A0acc += __shfl_xor(A0acc, 32, 64);
    A1acc += __shfl_xor(A1acc, 16, 64); A1acc += __shfl_xor(A1acc, 32, 64);
    const size_t blk = (size_t)b * KBMAX + kb;
    if (g == 0) {
        apart[blk * 128 + Mt * 64 + hqB] = A0acc;
        apart[blk * 128 + Mt * 64 + 32 + hqB] = A1acc;
    }
    {
        #pragma unroll
        for (int r = 0; r < 4; ++r) {
            int hq = MtV * 16 + g * 4 + r;
            unsigned* vp = vpart + (blk * 32 + hq) * 128 + li;
            #pragma unroll
            for (int ip = 0; ip < 4; ++ip) {
                unsigned u = pk2(av[2 * ip][r], av[2 * ip + 1][r]);
                int jp = (ntb >> 1) + ip;
                vp[jp * 16] = u;
            }
        }
    }
}

// ---------------------------------------------------------------------------
// V + A reduction: grid (32 b, 16). V rows 2/block; y==0 also reduces apart.
template<int KBMAX>
__global__ __launch_bounds__(256) void k_vred(
    const unsigned* __restrict__ vpart, const float* __restrict__ apart,
    float* __restrict__ V_g, float* __restrict__ A0_g, float* __restrict__ A1_g)
{
    const int t = threadIdx.x;
    const int b = blockIdx.x;
    const int hq = blockIdx.y * 2 + (t >> 7);
    const int tl = t & 127;
    const unsigned* p = vpart + ((size_t)(b * KBMAX) * 32 + hq) * 128 + tl;
    float lo = 0.f, hi = 0.f;
    #pragma unroll 8
    for (int kb = 0; kb < KBMAX; ++kb) {
        unsigned u = p[(size_t)kb * 4096];
        lo += bflo(u); hi += bfhi(u);
    }
    const int jp = tl >> 4, li = tl & 15;
    float* vo = V_g + ((size_t)b * 32 + hq) * 256 + jp * 32 + li;
    vo[0]  = lo;
    vo[16] = hi;

    if (blockIdx.y == 0 && t < 64) {
        float s = 0.f;
        const float* ap = apart + (size_t)(b * KBMAX) * 128 + t;
        #pragma unroll 8
        for (int kb = 0; kb < KBMAX; ++kb)
            s += ap[(size_t)kb * 128] + ap[(size_t)kb * 128 + 64];
        if (t < 32) A0_g[b * 32 + t] = s;
        else        A1_g[b * 32 + t - 32] = s;
    }
}

// ---------------------------------------------------------------------------
// gx | gh GEMMs. grid (6, 64). chunk-0 blocks zero slot_nxt (+ out_slots last iter).
__global__ __launch_bounds__(256) void k_gates(
    const float* __restrict__ V_g, const float* __restrict__ A0_g,
    const float* __restrict__ A1_g,
    const float* __restrict__ g_in, const float* __restrict__ b_in,
    const float* __restrict__ slot_cur,
    const unsigned* __restrict__ WfT2, const unsigned* __restrict__ WhhT2,
    float* __restrict__ gxh, float* __restrict__ slot_nxt,
    float* __restrict__ out_slots)
{
    __shared__ __align__(16) float aT[1024 * 4];
    const int t = threadIdx.x;
    const int rg = blockIdx.y;
    const int chunk = blockIdx.x;
    const int row0 = rg * 4;
    float acc0 = 0.f, acc1 = 0.f, acc2 = 0.f, acc3 = 0.f;

    if (chunk == 0) {
        #pragma unroll
        for (int rr = 0; rr < 4; ++rr) {
            slot_nxt[(size_t)(row0 + rr) * 256 + t] = 0.f;
            if (out_slots) out_slots[(size_t)(row0 + rr) * 256 + t] = 0.f;
        }
    }

    if (chunk < 3) {
        const int b = rg >> 1, qi0 = (rg & 1) * 4;
        const float gt = g_in[t], bt = b_in[t];
        #pragma unroll
        for (int kk = 0; kk < 4; ++kk) {
            float4 y4;
            #pragma unroll
            for (int rr = 0; rr < 4; ++rr) {
                int hq = kk * 8 + qi0 + rr;
                float A0 = A0_g[b * 32 + hq], A1 = A1_g[b * 32 + hq];
                float den = A0 + EPSR * (float)NKV;
                float vv = V_g[((size_t)b * 32 + hq) * 256 + t];
                float yv = (gt * (vv - A1) + bt * A0) / den;
                ((float*)&y4)[rr] = yv;
            }
            *(float4*)(aT + (kk * 256 + t) * 4) = y4;
        }
        __syncthreads();
        const unsigned* wp = WfT2 + chunk * 256 + t;
        #pragma unroll 4
        for (int k2 = 0; k2 < 512; ++k2) {
            unsigned wv = wp[(size_t)k2 * 768];
            float w0 = bflo(wv), w1 = bfhi(wv);
            float4 a0 = *(const float4*)(aT + 8 * k2);
            float4 a1 = *(const float4*)(aT + 8 * k2 + 4);
            acc0 = fmaf(a0.x, w0, acc0); acc0 = fmaf(a1.x, w1, acc0);
            acc1 = fmaf(a0.y, w0, acc1); acc1 = fmaf(a1.y, w1, acc1);
            acc2 = fmaf(a0.z, w0, acc2); acc2 = fmaf(a1.z, w1, acc2);
            acc3 = fmaf(a0.w, w0, acc3); acc3 = fmaf(a1.w, w1, acc3);
        }
        float* go = gxh + (size_t)row0 * 1536 + chunk * 256 + t;
        go[0] = acc0; go[1536] = acc1; go[3072] = acc2; go[4608] = acc3;
    } else {
        const int gc = chunk - 3;
        {
            float4 y4;
            #pragma unroll
            for (int rr = 0; rr < 4; ++rr)
                ((float*)&y4)[rr] = slot_cur[(size_t)(row0 + rr) * 256 + t];
            *(float4*)(aT + t * 4) = y4;
        }
        __syncthreads();
        const unsigned* wp = WhhT2 + gc * 256 + t;
        #pragma unroll 4
        for (int k2 = 0; k2 < 128; ++k2) {
            unsigned wv = wp[(size_t)k2 * 768];
            float w0 = bflo(wv), w1 = bfhi(wv);
            float4 a0 = *(const float4*)(aT + 8 * k2);
            float4 a1 = *(const float4*)(aT + 8 * k2 + 4);
            acc0 = fmaf(a0.x, w0, acc0); acc0 = fmaf(a1.x, w1, acc0);
            acc1 = fmaf(a0.y, w0, acc1); acc1 = fmaf(a1.y, w1, acc1);
            acc2 = fmaf(a0.z, w0, acc2); acc2 = fmaf(a1.z, w1, acc2);
            acc3 = fmaf(a0.w, w0, acc3); acc3 = fmaf(a1.w, w1, acc3);
        }
        float* go = gxh + (size_t)row0 * 1536 + 768 + gc * 256 + t;
        go[0] = acc0; go[1536] = acc1; go[3072] = acc2; go[4608] = acc3;
    }
}

// ---------------------------------------------------------------------------
// Fused GRU elementwise + LN + MLP(W1,relu,W2) with h1 in LDS. grid (4, 64).
__global__ __launch_bounds__(256) void k_mlp(
    const float* __restrict__ gxh, const float* __restrict__ slot_cur,
    const float* __restrict__ bih, const float* __restrict__ bhh,
    const float* __restrict__ gm, const float* __restrict__ bm,
    const unsigned* __restrict__ W1T2, const float* __restrict__ b1,
    const unsigned* __restrict__ W2T2, const float* __restrict__ b2,
    float* __restrict__ slot_nxt, float* __restrict__ out_slots)
{
    __shared__ __align__(16) float mT[1024];
    __shared__ float sm_l[4][256];
    __shared__ float h1_l[4][256];
    __shared__ float lnst[8];
    const int t = threadIdx.x;
    const int rg = blockIdx.y, chunk = blockIdx.x;
    const int row0 = rg * 4;
    const int lane = t & 63, w = t >> 6;

    const float bi0 = bih[t], bi1 = bih[256 + t], bi2 = bih[512 + t];
    const float bh0 = bhh[t], bh1 = bhh[256 + t], bh2 = bhh[512 + t];
    float smid[4];
    #pragma unroll
    for (int rr = 0; rr < 4; ++rr) {
        const float* gr = gxh + (size_t)(row0 + rr) * 1536;
        float gx0 = gr[t], gx1 = gr[256 + t], gx2 = gr[512 + t];
        float gh0 = gr[768 + t], gh1 = gr[1024 + t], gh2 = gr[1280 + t];
        float spv = slot_cur[(size_t)(row0 + rr) * 256 + t];
        float r = 1.f / (1.f + __expf(-(gx0 + bi0 + gh0 + bh0)));
        float z = 1.f / (1.f + __expf(-(gx1 + bi1 + gh1 + bh1)));
        float n = tanhf(gx2 + bi2 + r * (gh2 + bh2));
        smid[rr] = (1.f - z) * n + z * spv;
        sm_l[rr][t] = smid[rr];
    }
    __syncthreads();
    {
        float4 v = *(const float4*)(&sm_l[w][lane * 4]);
        float s0 = v.x + v.y + v.z + v.w;
        float s1 = v.x * v.x + v.y * v.y + v.z * v.z + v.w * v.w;
        #pragma unroll
        for (int o = 32; o >= 1; o >>= 1) { s0 += __shfl_xor(s0, o, 64); s1 += __shfl_xor(s1, o, 64); }
        if (lane == 0) {
            float mu = s0 * (1.f / 256.f);
            lnst[w * 2] = mu;
            lnst[w * 2 + 1] = rsqrtf(s1 * (1.f / 256.f) - mu * mu + 1e-5f);
        }
    }
    __syncthreads();
    {
        const float gmt = gm[t], bmt = bm[t];
        float4 m4;
        #pragma unroll
        for (int rr = 0; rr < 4; ++rr)
            ((float*)&m4)[rr] = (smid[rr] - lnst[rr * 2]) * lnst[rr * 2 + 1] * gmt + bmt;
        *(float4*)(mT + t * 4) = m4;
    }
    __syncthreads();

    {
        float acc0 = 0.f, acc1 = 0.f, acc2 = 0.f, acc3 = 0.f;
        const unsigned* wp = W1T2 + chunk * 256 + t;
        #pragma unroll 4
        for (int k2 = 0; k2 < 128; ++k2) {
            unsigned wv = wp[(size_t)k2 * 1024];
            float w0 = bflo(wv), w1 = bfhi(wv);
            float4 a0 = *(const float4*)(mT + 8 * k2);
            float4 a1 = *(const float4*)(mT + 8 * k2 + 4);
            acc0 = fmaf(a0.x, w0, acc0); acc0 = fmaf(a1.x, w1, acc0);
            acc1 = fmaf(a0.y, w0, acc1); acc1 = fmaf(a1.y, w1, acc1);
            acc2 = fmaf(a0.z, w0, acc2); acc2 = fmaf(a1.z, w1, acc2);
            acc3 = fmaf(a0.w, w0, acc3); acc3 = fmaf(a1.w, w1, acc3);
        }
        const float b1t = b1[chunk * 256 + t];
        h1_l[0][t] = fmaxf(acc0 + b1t, 0.f);
        h1_l[1][t] = fmaxf(acc1 + b1t, 0.f);
        h1_l[2][t] = fmaxf(acc2 + b1t, 0.f);
        h1_l[3][t] = fmaxf(acc3 + b1t, 0.f);
    }
    __syncthreads();

    {
        float o0 = 0.f, o1 = 0.f, o2 = 0.f, o3 = 0.f;
        const unsigned* wp = W2T2 + (size_t)(chunk * 128) * 256 + t;
        #pragma unroll 4
        for (int k2 = 0; k2 < 128; ++k2) {
            unsigned wv = wp[(size_t)k2 * 256];
            float w0 = bflo(wv), w1 = bfhi(wv);
            float a00 = h1_l[0][2 * k2], a01 = h1_l[0][2 * k2 + 1];
            float a10 = h1_l[1][2 * k2], a11 = h1_l[1][2 * k2 + 1];
            float a20 = h1_l[2][2 * k2], a21 = h1_l[2][2 * k2 + 1];
            float a30 = h1_l[3][2 * k2], a31 = h1_l[3][2 * k2 + 1];
            o0 = fmaf(a00, w0, o0); o0 = fmaf(a01, w1, o0);
            o1 = fmaf(a10, w0, o1); o1 = fmaf(a11, w1, o1);
            o2 = fmaf(a20, w0, o2); o2 = fmaf(a21, w1, o2);
            o3 = fmaf(a30, w0, o3); o3 = fmaf(a31, w1, o3);
        }
        const float b2t = b2[t];
        float p0 = o0 + ((chunk == 0) ? smid[0] + b2t : 0.f);
        float p1 = o1 + ((chunk == 0) ? smid[1] + b2t : 0.f);
        float p2 = o2 + ((chunk == 0) ? smid[2] + b2t : 0.f);
        float p3 = o3 + ((chunk == 0) ? smid[3] + b2t : 0.f);
        atomicAdd(slot_nxt + (size_t)(row0 + 0) * 256 + t, p0);
        atomicAdd(slot_nxt + (size_t)(row0 + 1) * 256 + t, p1);
        atomicAdd(slot_nxt + (size_t)(row0 + 2) * 256 + t, p2);
        atomicAdd(slot_nxt + (size_t)(row0 + 3) * 256 + t, p3);
        if (out_slots) {
            atomicAdd(out_slots + (size_t)(row0 + 0) * 256 + t, p0);
            atomicAdd(out_slots + (size_t)(row0 + 1) * 256 + t, p1);
            atomicAdd(out_slots + (size_t)(row0 + 2) * 256 + t, p2);
            atomicAdd(out_slots + (size_t)(row0 + 3) * 256 + t, p3);
        }
    }
}

// ---------------------------------------------------------------------------
extern "C" void kernel_launch(void* const* d_in, const int* in_sizes, int n_in,
                              void* d_out, int out_size, void* d_ws, size_t ws_size,
                              hipStream_t stream) {
    const float* inp     = (const float*)d_in[0];
    const float* slots0  = (const float*)d_in[1];
    const float* ln_in_g = (const float*)d_in[2];
    const float* ln_in_b = (const float*)d_in[3];
    const float* ln_s_g  = (const float*)d_in[4];
    const float* ln_s_b  = (const float*)d_in[5];
    const float* ln_m_g  = (const float*)d_in[6];
    const float* ln_m_b  = (const float*)d_in[7];
    const float* Wq  = (const float*)d_in[8];
    const float* Wk  = (const float*)d_in[9];
    const float* Wv  = (const float*)d_in[10];
    const float* Wih = (const float*)d_in[11];
    const float* Whh = (const float*)d_in[12];
    const float* bih = (const float*)d_in[13];
    const float* bhh = (const float*)d_in[14];
    const float* W1  = (const float*)d_in[15];
    const float* b1  = (const float*)d_in[16];
    const float* W2  = (const float*)d_in[17];
    const float* b2  = (const float*)d_in[18];

    float* ws = (float*)d_ws;
    float* V_g   = ws + WS_V;
    float* A0_g  = ws + WS_A0;
    float* A1_g  = ws + WS_A1;
    float* c0_g  = ws + WS_C0;
    float* c1_g  = ws + WS_C1;
    float* slotA = ws + WS_SLOTA;
    float* slotB = ws + WS_SLOTB;
    float* wqt   = ws + WS_WQT;
    float* gxh   = ws + WS_WPGXH;
    unsigned short* wp_bf = (unsigned short*)(ws + WS_WPGXH);
    unsigned* WfT2  = (unsigned*)(ws + WS_WFT);
    unsigned* WhhT2 = (unsigned*)(ws + WS_WHHT);
    unsigned* W1T2  = (unsigned*)(ws + WS_W1T);
    unsigned* W2T2  = (unsigned*)(ws + WS_W2T);
    float* rs_g  = ws + WS_RS;
    float* rm_g  = ws + WS_RM;
    unsigned* vpart = (unsigned*)(ws + WS_VPART);
    float* apart = ws + WS_APART;

    float* out_slots = (float*)d_out;
    float* out_vis   = out_slots + 32 * 8 * 256;
    float* out_temp  = out_vis + 32 * 4096 * 8;

    k_tr<<<dim3(8, 8), dim3(32, 8), 0, stream>>>(Wq, wqt, 256, 256);
    k_wfold<<<768, 256, 0, stream>>>(Wih, Wv, WfT2);
    k_trpack<<<128, 256, 0, stream>>>(Whh, WhhT2, 768, 256);
    k_trpack<<<128, 256, 0, stream>>>(W1, W1T2, 1024, 256);
    k_trpack<<<512, 256, 0, stream>>>(W2, W2T2, 256, 1024);
    k_copy<<<256, 256, 0, stream>>>(slots0, slotA, 65536);

    for (int it = 0; it < 3; ++it) {
        float* cur = (it & 1) ? slotB : slotA;
        float* nxt = (it & 1) ? slotA : slotB;
        k_prep<<<dim3(32, 4), 256, 0, stream>>>(cur, ln_s_g, ln_s_b, wqt, Wk,
                                                ln_in_g, ln_in_b, wp_bf, c0_g, c1_g);
        if (it == 0)
            k_attn<2, 1, 0><<<dim3(64, 32), 256, 0, stream>>>(
                inp, wp_bf, c0_g, c1_g, vpart, apart, rs_g, rm_g, out_vis, out_temp);
        else if (it == 1)
            k_attn<2, 0, 0><<<dim3(64, 32), 256, 0, stream>>>(
                inp, wp_bf, c0_g, c1_g, vpart, apart, rs_g, rm_g, out_vis, out_temp);
        else
            k_attn<2, 0, 1><<<dim3(64, 32), 256, 0, stream>>>(
                inp, wp_bf, c0_g, c1_g, vpart, apart, rs_g, rm_g, out_vis, out_temp);
        k_vred<64><<<dim3(32, 16), 256, 0, stream>>>(vpart, apart, V_g, A0_g, A1_g);
        k_gates<<<dim3(6, 64), 256, 0, stream>>>(
            V_g, A0_g, A1_g, ln_in_g, ln_in_b, cur, WfT2, WhhT2, gxh, nxt,
            (it == 2) ? out_slots : nullptr);
        k_mlp<<<dim3(4, 64), 256, 0, stream>>>(
            gxh, cur, bih, bhh, ln_m_g, ln_m_b, W1T2, b1, W2T2, b2, nxt,
            (it == 2) ? out_slots : nullptr);
    }
}

// Round 14
// 429.276 us; speedup vs baseline: 1.0773x; 1.0397x over previous
//
#include <hip/hip_runtime.h>
#include <math.h>

// ---------------------------------------------------------------------------
// SlotAttention fused forward. MFMA (bf16) attention path (r13 k_attn, proven).
//   Single fused k_setup (Wq^T | Wfold | WhhT2 | W1T2 | W2T2) in one launch.
//   iter0 reads slots0 directly (no copy); iter2 writes out_slots directly.
//   A0/A1: per-block partials (apart), V partials bf16 (vpart) -> k_vred.
//   GRU/MLP: gx = yflat @ Wfold^T; k_gates + fused k_mlp.
// ---------------------------------------------------------------------------

#define NKV   4096
#define DD    256
#define HQN   32
#define EPSR  1e-8f

// workspace layout (float offsets)
#define WS_V      0                     // 262144
#define WS_A0     262144                // 1024
#define WS_A1     263168                // 1024
#define WS_C0     264192                // 1024
#define WS_C1     265216                // 1024
#define WS_SLOTA  266240                // 65536
#define WS_SLOTB  331776                // 65536
#define WS_WQT    397312                // 65536 fp32 Wq^T
#define WS_WPGXH  462848                // 393216 (wp_bf 131072f | gxh [256][1536])
#define WS_WFT    856064                // 393216 uints: WfoldT2 [512][768]
#define WS_WHHT   1249280               // 98304 uints:  WhhT2   [128][768]
#define WS_W1T    1347584               // 131072 uints: W1T2    [128][1024]
#define WS_W2T    1478656               // 131072 uints: W2T2    [512][256]
#define WS_RS     1609728               // 131072 fp32 rs per token
#define WS_RM     1740800               // 131072 fp32 rm per token
#define WS_VPART  1871872               // 8388608 uints: Vpart bf16x2, 32MB
#define WS_APART  10260480              // 262144 fp32: apart[2048 blk][128]

typedef float f32x4 __attribute__((ext_vector_type(4)));
typedef short s16x8 __attribute__((ext_vector_type(8)));
typedef int   v2i   __attribute__((ext_vector_type(2)));

__device__ __forceinline__ unsigned bfr(float f) {
    unsigned u = __float_as_uint(f);
    return (u + 0x7fffu + ((u >> 16) & 1u)) >> 16;
}
__device__ __forceinline__ unsigned pk2(float lo, float hi) {
    return bfr(lo) | (bfr(hi) << 16);
}
__device__ __forceinline__ float bf2f(unsigned short us) {
    return __uint_as_float((unsigned)us << 16);
}
__device__ __forceinline__ float bflo(unsigned u) { return __uint_as_float(u << 16); }
__device__ __forceinline__ float bfhi(unsigned u) { return __uint_as_float(u & 0xffff0000u); }

__device__ __forceinline__ v2i tr_read(unsigned addr) {
    v2i d;
    asm volatile("ds_read_b64_tr_b16 %0, %1" : "=v"(d) : "v"(addr));
    return d;
}
__device__ __forceinline__ s16x8 mk_frag(v2i a, v2i b) {
    union { int i[4]; s16x8 s; } u;
    u.i[0] = a.x; u.i[1] = a.y; u.i[2] = b.x; u.i[3] = b.y;
    return u.s;
}

// ---------------------------------------------------------------------------
// Fused weight prep. grid 1600:
//   [0,64):    Wq -> wqt (32x32 tiled transpose)
//   [64,832):  Wfold row c (Wv folded into Wih)
//   [832,960): Whh -> WhhT2 pack
//   [960,1088): W1 -> W1T2 pack
//   [1088,1600): W2 -> W2T2 pack
__global__ __launch_bounds__(256) void k_setup(
    const float* __restrict__ Wq, const float* __restrict__ Wih,
    const float* __restrict__ Wv, const float* __restrict__ Whh,
    const float* __restrict__ W1, const float* __restrict__ W2,
    float* __restrict__ wqt, unsigned* __restrict__ WfT2,
    unsigned* __restrict__ WhhT2, unsigned* __restrict__ W1T2,
    unsigned* __restrict__ W2T2)
{
    const int blk = blockIdx.x;
    const int t = threadIdx.x;
    if (blk < 64) {
        __shared__ float tile[32][33];
        int bx = (blk & 7) * 32, by = (blk >> 3) * 32;
        int tx = t & 31, ty = t >> 5;
        #pragma unroll
        for (int k = 0; k < 32; k += 8)
            tile[ty + k][tx] = Wq[(size_t)(by + ty + k) * 256 + bx + tx];
        __syncthreads();
        #pragma unroll
        for (int k = 0; k < 32; k += 8)
            wqt[(size_t)(bx + ty + k) * 256 + by + tx] = tile[tx][ty + k];
    } else if (blk < 832) {
        const int c = blk - 64;
        __shared__ float wr[256];
        wr[t] = Wih[(size_t)c * 256 + t];
        __syncthreads();
        const float2* wv2 = (const float2*)Wv;
        #pragma unroll
        for (int pp = 0; pp < 2; ++pp) {
            int P = pp * 256 + t;
            int h = P >> 7, p = P & 127;
            float f0 = 0.f, f1 = 0.f;
            #pragma unroll 8
            for (int d = 0; d < 64; ++d) {
                float a = wr[h * 64 + d];
                float2 v = wv2[(size_t)(h * 64 + d) * 128 + p];
                f0 = fmaf(a, v.x, f0); f1 = fmaf(a, v.y, f1);
            }
            WfT2[(size_t)P * 768 + c] = pk2(f0, f1);
        }
    } else if (blk < 960) {
        const int c2 = blk - 832;
        #pragma unroll
        for (int q = 0; q < 3; ++q) {
            int r = q * 256 + t;
            WhhT2[(size_t)c2 * 768 + r] = pk2(Whh[(size_t)r * 256 + 2 * c2],
                                              Whh[(size_t)r * 256 + 2 * c2 + 1]);
        }
    } else if (blk < 1088) {
        const int c2 = blk - 960;
        #pragma unroll
        for (int q = 0; q < 4; ++q) {
            int r = q * 256 + t;
            W1T2[(size_t)c2 * 1024 + r] = pk2(W1[(size_t)r * 256 + 2 * c2],
                                              W1[(size_t)r * 256 + 2 * c2 + 1]);
        }
    } else {
        const int c2 = blk - 1088;
        W2T2[(size_t)c2 * 256 + t] = pk2(W2[(size_t)t * 1024 + 2 * c2],
                                         W2[(size_t)t * 1024 + 2 * c2 + 1]);
    }
}

// ---------------------------------------------------------------------------
// Merged slot prep: grid (32 b, 4 h).
__global__ __launch_bounds__(256) void k_prep(
    const float* __restrict__ slots, const float* __restrict__ g_s, const float* __restrict__ b_s,
    const float* __restrict__ wqt, const float* __restrict__ Wk,
    const float* __restrict__ g_in, const float* __restrict__ b_in,
    unsigned short* __restrict__ wp_bf, float* __restrict__ c0_g, float* __restrict__ c1_g)
{
    __shared__ float s_lds[2048];
    __shared__ float qs[512];
    __shared__ float redc[4096];
    const int t = threadIdx.x;
    const int b = blockIdx.x, h = blockIdx.y;
    const int lane = t & 63, w = t >> 6;
    const float LNS = 0.125f * 1.44269504f;

    for (int r = w; r < 8; r += 4) {
        const float4 v = ((const float4*)(slots + ((size_t)b * 8 + r) * 256))[lane];
        float s0 = v.x + v.y + v.z + v.w;
        float s1 = v.x * v.x + v.y * v.y + v.z * v.z + v.w * v.w;
        #pragma unroll
        for (int o = 32; o >= 1; o >>= 1) { s0 += __shfl_xor(s0, o, 64); s1 += __shfl_xor(s1, o, 64); }
        float m = s0 * (1.f / 256.f);
        float rs = rsqrtf(s1 * (1.f / 256.f) - m * m + 1e-5f);
        float4 gg = ((const float4*)g_s)[lane];
        float4 bb = ((const float4*)b_s)[lane];
        float4 nn;
        nn.x = (v.x - m) * rs * gg.x + bb.x;
        nn.y = (v.y - m) * rs * gg.y + bb.y;
        nn.z = (v.z - m) * rs * gg.z + bb.z;
        nn.w = (v.w - m) * rs * gg.w + bb.w;
        ((float4*)(s_lds + r * 256))[lane] = nn;
    }
    __syncthreads();

    {
        const int qi0 = t >> 6, d = t & 63;
        float a0 = 0.f, a1 = 0.f;
        #pragma unroll 8
        for (int j = 0; j < 256; ++j) {
            float wv = wqt[j * 256 + h * 64 + d];
            a0 = fmaf(s_lds[qi0 * 256 + j], wv, a0);
            a1 = fmaf(s_lds[(qi0 + 4) * 256 + j], wv, a1);
        }
        qs[qi0 * 64 + d] = a0;
        qs[(qi0 + 4) * 64 + d] = a1;
    }
    __syncthreads();

    float a2[8];
    #pragma unroll
    for (int qi = 0; qi < 8; ++qi) a2[qi] = 0.f;
    #pragma unroll 4
    for (int d = 0; d < 64; ++d) {
        float wv = Wk[(size_t)(h * 64 + d) * 256 + t];
        #pragma unroll
        for (int qi = 0; qi < 8; ++qi) a2[qi] = fmaf(qs[qi * 64 + d], wv, a2[qi]);
    }
    const float gv = g_in[t], bv = b_in[t];
    #pragma unroll
    for (int qi = 0; qi < 8; ++qi) {
        float kv = LNS * a2[qi];
        float we = kv * gv;
        wp_bf[((size_t)b * HQN + h * 8 + qi) * 256 + t] = (unsigned short)bfr(we);
        redc[qi * 256 + t] = we;
        redc[2048 + qi * 256 + t] = kv * bv;
    }
    __syncthreads();
    #pragma unroll
    for (int rep = 0; rep < 2; ++rep) {
        int r = w * 2 + rep;
        float sv1 = redc[r * 256 + lane] + redc[r * 256 + 64 + lane] +
                    redc[r * 256 + 128 + lane] + redc[r * 256 + 192 + lane];
        float sv0 = redc[2048 + r * 256 + lane] + redc[2048 + r * 256 + 64 + lane] +
                    redc[2048 + r * 256 + 128 + lane] + redc[2048 + r * 256 + 192 + lane];
        #pragma unroll
        for (int o = 32; o >= 1; o >>= 1) {
            sv1 += __shfl_xor(sv1, o, 64);
            sv0 += __shfl_xor(sv0, o, 64);
        }
        if (lane == 0) {
            c1_g[b * 32 + h * 8 + r] = sv1;
            c0_g[b * 32 + h * 8 + r] = sv0;
        }
    }
}

// ---------------------------------------------------------------------------
// k_attn helpers
__device__ __forceinline__ void load_x(const float* __restrict__ inp, int b, int n0,
                                       int tok_s, int seg8, float4* ld) {
    const float4* row4 = (const float4*)(inp + ((size_t)b * NKV + n0 + tok_s) * 256);
    #pragma unroll
    for (int u = 0; u < 8; ++u) ld[u] = row4[(u >> 2) * 32 + seg8 * 4 + (u & 3)];
}

__device__ __forceinline__ void pack_x(const float4* ld, char* dst, int tok_s, int seg8) {
    #pragma unroll
    for (int c = 0; c < 2; ++c) {
        int nt = seg8 + 8 * c;
        #pragma unroll
        for (int h = 0; h < 2; ++h) {
            float4 fa = ld[c * 4 + h * 2], fb = ld[c * 4 + h * 2 + 1];
            uint4 pk;
            pk.x = pk2(fa.x, fa.y); pk.y = pk2(fa.z, fa.w);
            pk.z = pk2(fb.x, fb.y); pk.w = pk2(fb.z, fb.w);
            *(uint4*)(dst + nt * 1040 + tok_s * 32 + h * 16) = pk;
        }
    }
}

__device__ __forceinline__ void calc_stats(const float4* ld, float* sb,
                                           float* __restrict__ rs_g, float* __restrict__ rm_g,
                                           int b, int n0, int tok_s, int seg8) {
    float s0 = 0.f, s1 = 0.f;
    #pragma unroll
    for (int u = 0; u < 8; ++u) {
        float4 v = ld[u];
        s0 += v.x + v.y + v.z + v.w;
        s1 = fmaf(v.x, v.x, s1); s1 = fmaf(v.y, v.y, s1);
        s1 = fmaf(v.z, v.z, s1); s1 = fmaf(v.w, v.w, s1);
    }
    s0 += __shfl_xor(s0, 1, 64); s1 += __shfl_xor(s1, 1, 64);
    s0 += __shfl_xor(s0, 2, 64); s1 += __shfl_xor(s1, 2, 64);
    s0 += __shfl_xor(s0, 4, 64); s1 += __shfl_xor(s1, 4, 64);
    float m  = s0 * (1.f / 256.f);
    float rs = rsqrtf(s1 * (1.f / 256.f) - m * m + 1e-5f);
    if (seg8 == 0) {
        sb[tok_s] = rs;
        sb[32 + tok_s] = rs * m;
        rs_g[b * 4096 + n0 + tok_s] = rs;
        rm_g[b * 4096 + n0 + tok_s] = rs * m;
    }
}

// ---------------------------------------------------------------------------
// Main fused MFMA pass (r13 structure, unchanged). grid (64, 32), NC=2.
template<int NC, int STATS, int WVIS>
__global__ __launch_bounds__(256) void k_attn(
    const float* __restrict__ inp, const unsigned short* __restrict__ wp_bf,
    const float* __restrict__ c0_g, const float* __restrict__ c1_g,
    unsigned* __restrict__ vpart, float* __restrict__ apart,
    float* __restrict__ rs_g, float* __restrict__ rm_g,
    float* __restrict__ out_vis, float* __restrict__ out_temp)
{
    constexpr int KBMAX = 128 / NC;
    __shared__ unsigned short xb[8320];
    __shared__ unsigned short wl[8192];
    __shared__ unsigned short pt[1024];
    __shared__ float stats[2][64];

    const int t = threadIdx.x;
    const int l = t & 63, w = t >> 6;
    const int g = l >> 4, li = l & 15;
    const int b = blockIdx.y, kb = blockIdx.x;

    char* xbB = (char*)xb;
    char* wlB = (char*)wl;
    char* ptB = (char*)pt;
    const int tok_s = t >> 3, seg8 = t & 7;
    const int cbase = kb * NC;

    {
        const uint4* wp4 = (const uint4*)wp_bf + ((size_t)b * 8192 + (t >> 3) * 256 + (t & 7) * 32) / 8;
        const int hq = t >> 3, sg = t & 7;
        #pragma unroll
        for (int q = 0; q < 4; ++q) {
            uint4 v = wp4[q];
            *(uint4*)(wlB + hq * 512 + (((sg * 4 + q) ^ (hq & 7)) * 16)) = v;
        }
    }

    const int Mt = w & 1, Nt = w >> 1;
    const int hqB = Nt * 16 + li;
    const int hq0 = li, hq1 = 16 + li;
    const float c0h0 = c0_g[b * 32 + hq0], c1h0 = c1_g[b * 32 + hq0];
    const float c0h1 = c0_g[b * 32 + hq1], c1h1 = c1_g[b * 32 + hq1];
    const int MtV = w >> 1, ntb = (w & 1) * 8;
    const int hqA = MtV * 16 + li;

    f32x4 av[8];
    #pragma unroll
    for (int u = 0; u < 8; ++u) av[u] = (f32x4){0.f, 0.f, 0.f, 0.f};
    float A0acc = 0.f, A1acc = 0.f;

    const unsigned xbase = (unsigned)(uintptr_t)xbB;

    {
        float4 ldA[8];
        load_x(inp, b, cbase * 32, tok_s, seg8, ldA);
        if (STATS) {
            calc_stats(ldA, &stats[0][0], rs_g, rm_g, b, cbase * 32, tok_s, seg8);
        } else {
            if (t < 32) stats[0][t] = rs_g[b * 4096 + cbase * 32 + t];
            else if (t < 64) stats[0][t] = rm_g[b * 4096 + cbase * 32 + t - 32];
        }
        pack_x(ldA, xbB, tok_s, seg8);
    }
    __syncthreads();   // A

    #pragma unroll
    for (int ci = 0; ci < NC; ++ci) {
        const int cur = ci & 1, nxt = cur ^ 1;
        const int n0 = (cbase + ci) * 32;

        float4 ldN[8];
        if (ci < NC - 1) load_x(inp, b, n0 + 32, tok_s, seg8, ldN);
        __builtin_amdgcn_sched_barrier(0);

        f32x4 accS0 = (f32x4){0.f, 0.f, 0.f, 0.f};
        f32x4 accS1 = (f32x4){0.f, 0.f, 0.f, 0.f};
        __builtin_amdgcn_s_setprio(1);
        #pragma unroll
        for (int kk = 0; kk < 8; ++kk) {
            s16x8 af = *(const s16x8*)(xbB + (kk * 2 + (g >> 1)) * 1040 +
                                       (Mt * 16 + li) * 32 + (g & 1) * 16);
            s16x8 bf0 = *(const s16x8*)(wlB + hq0 * 512 + (((kk * 4 + g) ^ (hq0 & 7)) * 16));
            s16x8 bf1 = *(const s16x8*)(wlB + hq1 * 512 + (((kk * 4 + g) ^ (hq1 & 7)) * 16));
            accS0 = __builtin_amdgcn_mfma_f32_16x16x32_bf16(af, bf0, accS0, 0, 0, 0);
            accS1 = __builtin_amdgcn_mfma_f32_16x16x32_bf16(af, bf1, accS1, 0, 0, 0);
        }
        __builtin_amdgcn_s_setprio(0);

        float aaW[4], rsv[4], rmv[4];
        #pragma unroll
        for (int r = 0; r < 4; ++r) {
            int tokr = Mt * 16 + g * 4 + r;
            rsv[r] = stats[cur][tokr];
            rmv[r] = stats[cur][32 + tokr];
            float lg0 = fmaf(rsv[r], accS0[r], fmaf(-rmv[r], c1h0, c0h0));
            float lg1 = fmaf(rsv[r], accS1[r], fmaf(-rmv[r], c1h1, c0h1));
            float v = fmaxf(lg0, lg1);
            v = fmaxf(v, __shfl_xor(v, 1, 64));
            v = fmaxf(v, __shfl_xor(v, 2, 64));
            v = fmaxf(v, __shfl_xor(v, 4, 64));
            v = fmaxf(v, __shfl_xor(v, 8, 64));
            float ex0 = exp2f(lg0 - v);
            float ex1 = exp2f(lg1 - v);
            float s = ex0 + ex1;
            s += __shfl_xor(s, 1, 64);
            s += __shfl_xor(s, 2, 64);
            s += __shfl_xor(s, 4, 64);
            s += __shfl_xor(s, 8, 64);
            float inv = 1.f / s;
            float aw = (Nt ? ex1 : ex0) * inv;
            A0acc += aw;
            A1acc = fmaf(aw, rmv[r], A1acc);
            aaW[r] = aw * rsv[r];
        }
        {
            uint2 pw;
            pw.x = pk2(aaW[0], aaW[1]);
            pw.y = pk2(aaW[2], aaW[3]);
            int tokb = Mt * 16 + g * 4;
            int slot = (tokb >> 3) ^ ((hqB >> 1) & 3);
            *(uint2*)(ptB + hqB * 64 + slot * 16 + (tokb & 7) * 2) = pw;
        }
        __syncthreads();   // D

        if (WVIS) {
            int tk = t >> 3, q = t & 7;
            float sv = 0.f;
            #pragma unroll
            for (int h = 0; h < 4; ++h) {
                int hq = h * 8 + q;
                int slot = (tk >> 3) ^ ((hq >> 1) & 3);
                sv += bf2f(*(const unsigned short*)(ptB + hq * 64 + slot * 16 + (tk & 7) * 2));
            }
            float vv = sv / stats[cur][tk];
            size_t o = ((size_t)b * NKV + n0 + tk) * 8 + q;
            out_vis[o] = vv; out_temp[o] = vv;
        }

        if (ci < NC - 1) {
            if (STATS) {
                calc_stats(ldN, &stats[nxt][0], rs_g, rm_g, b, n0 + 32, tok_s, seg8);
            } else {
                if (t < 32) stats[nxt][t] = rs_g[b * 4096 + n0 + 32 + t];
                else if (t < 64) stats[nxt][t] = rm_g[b * 4096 + n0 + 32 + t - 32];
            }
        }

        {
            s16x8 pa = *(const s16x8*)(ptB + hqA * 64 + ((g ^ ((hqA >> 1) & 3)) * 16));
            unsigned abase = xbase + g * 256 + li * 8;
            v2i t0a = tr_read(abase + (ntb + 0) * 1040);
            v2i t0b = tr_read(abase + (ntb + 0) * 1040 + 128);
            v2i t1a = tr_read(abase + (ntb + 1) * 1040);
            v2i t1b = tr_read(abase + (ntb + 1) * 1040 + 128);
            v2i t2a = tr_read(abase + (ntb + 2) * 1040);
            v2i t2b = tr_read(abase + (ntb + 2) * 1040 + 128);
            v2i t3a = tr_read(abase + (ntb + 3) * 1040);
            v2i t3b = tr_read(abase + (ntb + 3) * 1040 + 128);
            asm volatile("s_waitcnt lgkmcnt(0)" ::: "memory");
            __builtin_amdgcn_sched_barrier(0);
            __builtin_amdgcn_s_setprio(1);
            av[0] = __builtin_amdgcn_mfma_f32_16x16x32_bf16(pa, mk_frag(t0a, t0b), av[0], 0, 0, 0);
            av[1] = __builtin_amdgcn_mfma_f32_16x16x32_bf16(pa, mk_frag(t1a, t1b), av[1], 0, 0, 0);
            av[2] = __builtin_amdgcn_mfma_f32_16x16x32_bf16(pa, mk_frag(t2a, t2b), av[2], 0, 0, 0);
            av[3] = __builtin_amdgcn_mfma_f32_16x16x32_bf16(pa, mk_frag(t3a, t3b), av[3], 0, 0, 0);
            __builtin_amdgcn_s_setprio(0);
            v2i t4a = tr_read(abase + (ntb + 4) * 1040);
            v2i t4b = tr_read(abase + (ntb + 4) * 1040 + 128);
            v2i t5a = tr_read(abase + (ntb + 5) * 1040);
            v2i t5b = tr_read(abase + (ntb + 5) * 1040 + 128);
            v2i t6a = tr_read(abase + (ntb + 6) * 1040);
            v2i t6b = tr_read(abase + (ntb + 6) * 1040 + 128);
            v2i t7a = tr_read(abase + (ntb + 7) * 1040);
            v2i t7b = tr_read(abase + (ntb + 7) * 1040 + 128);
            asm volatile("s_waitcnt lgkmcnt(0)" ::: "memory");
            __builtin_amdgcn_sched_barrier(0);
            __builtin_amdgcn_s_setprio(1);
            av[4] = __builtin_amdgcn_mfma_f32_16x16x32_bf16(pa, mk_frag(t4a, t4b), av[4], 0, 0, 0);
            av[5] = __builtin_amdgcn_mfma_f32_16x16x32_bf16(pa, mk_frag(t5a, t5b), av[5], 0, 0, 0);
            av[6] = __builtin_amdgcn_mfma_f32_16x16x32_bf16(pa, mk_frag(t6a, t6b), av[6], 0, 0, 0);
            av[7] = __builtin_amdgcn_mfma_f32_16x16x32_bf16(pa, mk_frag(t7a, t7b), av[7], 0, 0, 0);
            __builtin_amdgcn_s_setprio(0);
        }
        __syncthreads();   // E

        if (ci < NC - 1) {
            pack_x(ldN, xbB, tok_s, seg8);
            __syncthreads();   // A
        }
    }

    A0acc += __shfl_xor(A0acc, 16, 64); A0acc += __shfl_xor(A0acc, 32, 64);
    A1acc += __shfl_xor(A1acc, 16, 64); A1acc += __shfl_xor(A1acc, 32, 64);
    const size_t blk = (size_t)b * KBMAX + kb;
    if (g == 0) {
        apart[blk * 128 + Mt * 64 + hqB] = A0acc;
        apart[blk * 128 + Mt * 64 + 32 + hqB] = A1acc;
    }
    {
        #pragma unroll
        for (int r = 0; r < 4; ++r) {
            int hq = MtV * 16 + g * 4 + r;
            unsigned* vp = vpart + (blk * 32 + hq) * 128 + li;
            #pragma unroll
            for (int ip = 0; ip < 4; ++ip) {
                unsigned u = pk2(av[2 * ip][r], av[2 * ip + 1][r]);
                int jp = (ntb >> 1) + ip;
                vp[jp * 16] = u;
            }
        }
    }
}

// ---------------------------------------------------------------------------
// V + A reduction: grid (32 b, 16).
template<int KBMAX>
__global__ __launch_bounds__(256) void k_vred(
    const unsigned* __restrict__ vpart, const float* __restrict__ apart,
    float* __restrict__ V_g, float* __restrict__ A0_g, float* __restrict__ A1_g)
{
    const int t = threadIdx.x;
    const int b = blockIdx.x;
    const int hq = blockIdx.y * 2 + (t >> 7);
    const int tl = t & 127;
    const unsigned* p = vpart + ((size_t)(b * KBMAX) * 32 + hq) * 128 + tl;
    float lo = 0.f, hi = 0.f;
    #pragma unroll 8
    for (int kb = 0; kb < KBMAX; ++kb) {
        unsigned u = p[(size_t)kb * 4096];
        lo += bflo(u); hi += bfhi(u);
    }
    const int jp = tl >> 4, li = tl & 15;
    float* vo = V_g + ((size_t)b * 32 + hq) * 256 + jp * 32 + li;
    vo[0]  = lo;
    vo[16] = hi;

    if (blockIdx.y == 0 && t < 64) {
        float s = 0.f;
        const float* ap = apart + (size_t)(b * KBMAX) * 128 + t;
        #pragma unroll 8
        for (int kb = 0; kb < KBMAX; ++kb)
            s += ap[(size_t)kb * 128] + ap[(size_t)kb * 128 + 64];
        if (t < 32) A0_g[b * 32 + t] = s;
        else        A1_g[b * 32 + t - 32] = s;
    }
}

// ---------------------------------------------------------------------------
// gx | gh GEMMs. grid (6, 64). chunk-0 blocks zero slot_nxt.
__global__ __launch_bounds__(256) void k_gates(
    const float* __restrict__ V_g, const float* __restrict__ A0_g,
    const float* __restrict__ A1_g,
    const float* __restrict__ g_in, const float* __restrict__ b_in,
    const float* __restrict__ slot_cur,
    const unsigned* __restrict__ WfT2, const unsigned* __restrict__ WhhT2,
    float* __restrict__ gxh, float* __restrict__ slot_nxt)
{
    __shared__ __align__(16) float aT[1024 * 4];
    const int t = threadIdx.x;
    const int rg = blockIdx.y;
    const int chunk = blockIdx.x;
    const int row0 = rg * 4;
    float acc0 = 0.f, acc1 = 0.f, acc2 = 0.f, acc3 = 0.f;

    if (chunk == 0) {
        #pragma unroll
        for (int rr = 0; rr < 4; ++rr)
            slot_nxt[(size_t)(row0 + rr) * 256 + t] = 0.f;
    }

    if (chunk < 3) {
        const int b = rg >> 1, qi0 = (rg & 1) * 4;
        const float gt = g_in[t], bt = b_in[t];
        #pragma unroll
        for (int kk = 0; kk < 4; ++kk) {
            float4 y4;
            #pragma unroll
            for (int rr = 0; rr < 4; ++rr) {
                int hq = kk * 8 + qi0 + rr;
                float A0 = A0_g[b * 32 + hq], A1 = A1_g[b * 32 + hq];
                float den = A0 + EPSR * (float)NKV;
                float vv = V_g[((size_t)b * 32 + hq) * 256 + t];
                float yv = (gt * (vv - A1) + bt * A0) / den;
                ((float*)&y4)[rr] = yv;
            }
            *(float4*)(aT + (kk * 256 + t) * 4) = y4;
        }
        __syncthreads();
        const unsigned* wp = WfT2 + chunk * 256 + t;
        #pragma unroll 4
        for (int k2 = 0; k2 < 512; ++k2) {
            unsigned wv = wp[(size_t)k2 * 768];
            float w0 = bflo(wv), w1 = bfhi(wv);
            float4 a0 = *(const float4*)(aT + 8 * k2);
            float4 a1 = *(const float4*)(aT + 8 * k2 + 4);
            acc0 = fmaf(a0.x, w0, acc0); acc0 = fmaf(a1.x, w1, acc0);
            acc1 = fmaf(a0.y, w0, acc1); acc1 = fmaf(a1.y, w1, acc1);
            acc2 = fmaf(a0.z, w0, acc2); acc2 = fmaf(a1.z, w1, acc2);
            acc3 = fmaf(a0.w, w0, acc3); acc3 = fmaf(a1.w, w1, acc3);
        }
        float* go = gxh + (size_t)row0 * 1536 + chunk * 256 + t;
        go[0] = acc0; go[1536] = acc1; go[3072] = acc2; go[4608] = acc3;
    } else {
        const int gc = chunk - 3;
        {
            float4 y4;
            #pragma unroll
            for (int rr = 0; rr < 4; ++rr)
                ((float*)&y4)[rr] = slot_cur[(size_t)(row0 + rr) * 256 + t];
            *(float4*)(aT + t * 4) = y4;
        }
        __syncthreads();
        const unsigned* wp = WhhT2 + gc * 256 + t;
        #pragma unroll 4
        for (int k2 = 0; k2 < 128; ++k2) {
            unsigned wv = wp[(size_t)k2 * 768];
            float w0 = bflo(wv), w1 = bfhi(wv);
            float4 a0 = *(const float4*)(aT + 8 * k2);
            float4 a1 = *(const float4*)(aT + 8 * k2 + 4);
            acc0 = fmaf(a0.x, w0, acc0); acc0 = fmaf(a1.x, w1, acc0);
            acc1 = fmaf(a0.y, w0, acc1); acc1 = fmaf(a1.y, w1, acc1);
            acc2 = fmaf(a0.z, w0, acc2); acc2 = fmaf(a1.z, w1, acc2);
            acc3 = fmaf(a0.w, w0, acc3); acc3 = fmaf(a1.w, w1, acc3);
        }
        float* go = gxh + (size_t)row0 * 1536 + 768 + gc * 256 + t;
        go[0] = acc0; go[1536] = acc1; go[3072] = acc2; go[4608] = acc3;
    }
}

// ---------------------------------------------------------------------------
// Fused GRU elementwise + LN + MLP(W1,relu,W2) with h1 in LDS. grid (4, 64).
__global__ __launch_bounds__(256) void k_mlp(
    const float* __restrict__ gxh, const float* __restrict__ slot_cur,
    const float* __restrict__ bih, const float* __restrict__ bhh,
    const float* __restrict__ gm, const float* __restrict__ bm,
    const unsigned* __restrict__ W1T2, const float* __restrict__ b1,
    const unsigned* __restrict__ W2T2, const float* __restrict__ b2,
    float* __restrict__ slot_nxt)
{
    __shared__ __align__(16) float mT[1024];
    __shared__ float sm_l[4][256];
    __shared__ float h1_l[4][256];
    __shared__ float lnst[8];
    const int t = threadIdx.x;
    const int rg = blockIdx.y, chunk = blockIdx.x;
    const int row0 = rg * 4;
    const int lane = t & 63, w = t >> 6;

    const float bi0 = bih[t], bi1 = bih[256 + t], bi2 = bih[512 + t];
    const float bh0 = bhh[t], bh1 = bhh[256 + t], bh2 = bhh[512 + t];
    float smid[4];
    #pragma unroll
    for (int rr = 0; rr < 4; ++rr) {
        const float* gr = gxh + (size_t)(row0 + rr) * 1536;
        float gx0 = gr[t], gx1 = gr[256 + t], gx2 = gr[512 + t];
        float gh0 = gr[768 + t], gh1 = gr[1024 + t], gh2 = gr[1280 + t];
        float spv = slot_cur[(size_t)(row0 + rr) * 256 + t];
        float r = 1.f / (1.f + __expf(-(gx0 + bi0 + gh0 + bh0)));
        float z = 1.f / (1.f + __expf(-(gx1 + bi1 + gh1 + bh1)));
        float n = tanhf(gx2 + bi2 + r * (gh2 + bh2));
        smid[rr] = (1.f - z) * n + z * spv;
        sm_l[rr][t] = smid[rr];
    }
    __syncthreads();
    {
        float4 v = *(const float4*)(&sm_l[w][lane * 4]);
        float s0 = v.x + v.y + v.z + v.w;
        float s1 = v.x * v.x + v.y * v.y + v.z * v.z + v.w * v.w;
        #pragma unroll
        for (int o = 32; o >= 1; o >>= 1) { s0 += __shfl_xor(s0, o, 64); s1 += __shfl_xor(s1, o, 64); }
        if (lane == 0) {
            float mu = s0 * (1.f / 256.f);
            lnst[w * 2] = mu;
            lnst[w * 2 + 1] = rsqrtf(s1 * (1.f / 256.f) - mu * mu + 1e-5f);
        }
    }
    __syncthreads();
    {
        const float gmt = gm[t], bmt = bm[t];
        float4 m4;
        #pragma unroll
        for (int rr = 0; rr < 4; ++rr)
            ((float*)&m4)[rr] = (smid[rr] - lnst[rr * 2]) * lnst[rr * 2 + 1] * gmt + bmt;
        *(float4*)(mT + t * 4) = m4;
    }
    __syncthreads();

    {
        float acc0 = 0.f, acc1 = 0.f, acc2 = 0.f, acc3 = 0.f;
        const unsigned* wp = W1T2 + chunk * 256 + t;
        #pragma unroll 4
        for (int k2 = 0; k2 < 128; ++k2) {
            unsigned wv = wp[(size_t)k2 * 1024];
            float w0 = bflo(wv), w1 = bfhi(wv);
            float4 a0 = *(const float4*)(mT + 8 * k2);
            float4 a1 = *(const float4*)(mT + 8 * k2 + 4);
            acc0 = fmaf(a0.x, w0, acc0); acc0 = fmaf(a1.x, w1, acc0);
            acc1 = fmaf(a0.y, w0, acc1); acc1 = fmaf(a1.y, w1, acc1);
            acc2 = fmaf(a0.z, w0, acc2); acc2 = fmaf(a1.z, w1, acc2);
            acc3 = fmaf(a0.w, w0, acc3); acc3 = fmaf(a1.w, w1, acc3);
        }
        const float b1t = b1[chunk * 256 + t];
        h1_l[0][t] = fmaxf(acc0 + b1t, 0.f);
        h1_l[1][t] = fmaxf(acc1 + b1t, 0.f);
        h1_l[2][t] = fmaxf(acc2 + b1t, 0.f);
        h1_l[3][t] = fmaxf(acc3 + b1t, 0.f);
    }
    __syncthreads();

    {
        float o0 = 0.f, o1 = 0.f, o2 = 0.f, o3 = 0.f;
        const unsigned* wp = W2T2 + (size_t)(chunk * 128) * 256 + t;
        #pragma unroll 4
        for (int k2 = 0; k2 < 128; ++k2) {
            unsigned wv = wp[(size_t)k2 * 256];
            float w0 = bflo(wv), w1 = bfhi(wv);
            float a00 = h1_l[0][2 * k2], a01 = h1_l[0][2 * k2 + 1];
            float a10 = h1_l[1][2 * k2], a11 = h1_l[1][2 * k2 + 1];
            float a20 = h1_l[2][2 * k2], a21 = h1_l[2][2 * k2 + 1];
            float a30 = h1_l[3][2 * k2], a31 = h1_l[3][2 * k2 + 1];
            o0 = fmaf(a00, w0, o0); o0 = fmaf(a01, w1, o0);
            o1 = fmaf(a10, w0, o1); o1 = fmaf(a11, w1, o1);
            o2 = fmaf(a20, w0, o2); o2 = fmaf(a21, w1, o2);
            o3 = fmaf(a30, w0, o3); o3 = fmaf(a31, w1, o3);
        }
        const float b2t = b2[t];
        float p0 = o0 + ((chunk == 0) ? smid[0] + b2t : 0.f);
        float p1 = o1 + ((chunk == 0) ? smid[1] + b2t : 0.f);
        float p2 = o2 + ((chunk == 0) ? smid[2] + b2t : 0.f);
        float p3 = o3 + ((chunk == 0) ? smid[3] + b2t : 0.f);
        atomicAdd(slot_nxt + (size_t)(row0 + 0) * 256 + t, p0);
        atomicAdd(slot_nxt + (size_t)(row0 + 1) * 256 + t, p1);
        atomicAdd(slot_nxt + (size_t)(row0 + 2) * 256 + t, p2);
        atomicAdd(slot_nxt + (size_t)(row0 + 3) * 256 + t, p3);
    }
}

// ---------------------------------------------------------------------------
extern "C" void kernel_launch(void* const* d_in, const int* in_sizes, int n_in,
                              void* d_out, int out_size, void* d_ws, size_t ws_size,
                              hipStream_t stream) {
    const float* inp     = (const float*)d_in[0];
    const float* slots0  = (const float*)d_in[1];
    const float* ln_in_g = (const float*)d_in[2];
    const float* ln_in_b = (const float*)d_in[3];
    const float* ln_s_g  = (const float*)d_in[4];
    const float* ln_s_b  = (const float*)d_in[5];
    const float* ln_m_g  = (const float*)d_in[6];
    const float* ln_m_b  = (const float*)d_in[7];
    const float* Wq  = (const float*)d_in[8];
    const float* Wk  = (const float*)d_in[9];
    const float* Wv  = (const float*)d_in[10];
    const float* Wih = (const float*)d_in[11];
    const float* Whh = (const float*)d_in[12];
    const float* bih = (const float*)d_in[13];
    const float* bhh = (const float*)d_in[14];
    const float* W1  = (const float*)d_in[15];
    const float* b1  = (const float*)d_in[16];
    const float* W2  = (const float*)d_in[17];
    const float* b2  = (const float*)d_in[18];

    float* ws = (float*)d_ws;
    float* V_g   = ws + WS_V;
    float* A0_g  = ws + WS_A0;
    float* A1_g  = ws + WS_A1;
    float* c0_g  = ws + WS_C0;
    float* c1_g  = ws + WS_C1;
    float* slotA = ws + WS_SLOTA;
    float* slotB = ws + WS_SLOTB;
    float* wqt   = ws + WS_WQT;
    float* gxh   = ws + WS_WPGXH;
    unsigned short* wp_bf = (unsigned short*)(ws + WS_WPGXH);
    unsigned* WfT2  = (unsigned*)(ws + WS_WFT);
    unsigned* WhhT2 = (unsigned*)(ws + WS_WHHT);
    unsigned* W1T2  = (unsigned*)(ws + WS_W1T);
    unsigned* W2T2  = (unsigned*)(ws + WS_W2T);
    float* rs_g  = ws + WS_RS;
    float* rm_g  = ws + WS_RM;
    unsigned* vpart = (unsigned*)(ws + WS_VPART);
    float* apart = ws + WS_APART;

    float* out_slots = (float*)d_out;
    float* out_vis   = out_slots + 32 * 8 * 256;
    float* out_temp  = out_vis + 32 * 4096 * 8;

    k_setup<<<1600, 256, 0, stream>>>(Wq, Wih, Wv, Whh, W1, W2,
                                      wqt, WfT2, WhhT2, W1T2, W2T2);

    for (int it = 0; it < 3; ++it) {
        const float* cur = (it == 0) ? slots0 : ((it == 1) ? slotB : slotA);
        float* nxt = (it == 0) ? slotB : ((it == 1) ? slotA : out_slots);
        k_prep<<<dim3(32, 4), 256, 0, stream>>>(cur, ln_s_g, ln_s_b, wqt, Wk,
                                                ln_in_g, ln_in_b, wp_bf, c0_g, c1_g);
        if (it == 0)
            k_attn<2, 1, 0><<<dim3(64, 32), 256, 0, stream>>>(
                inp, wp_bf, c0_g, c1_g, vpart, apart, rs_g, rm_g, out_vis, out_temp);
        else if (it == 1)
            k_attn<2, 0, 0><<<dim3(64, 32), 256, 0, stream>>>(
                inp, wp_bf, c0_g, c1_g, vpart, apart, rs_g, rm_g, out_vis, out_temp);
        else
            k_attn<2, 0, 1><<<dim3(64, 32), 256, 0, stream>>>(
                inp, wp_bf, c0_g, c1_g, vpart, apart, rs_g, rm_g, out_vis, out_temp);
        k_vred<64><<<dim3(32, 16), 256, 0, stream>>>(vpart, apart, V_g, A0_g, A1_g);
        k_gates<<<dim3(6, 64), 256, 0, stream>>>(
            V_g, A0_g, A1_g, ln_in_g, ln_in_b, cur, WfT2, WhhT2, gxh, nxt);
        k_mlp<<<dim3(4, 64), 256, 0, stream>>>(
            gxh, cur, bih, bhh, ln_m_g, ln_m_b, W1T2, b1, W2T2, b2, nxt);
    }
}